// Round 7
// baseline (1340.541 us; speedup 1.0000x reference)
//
#include <hip/hip_runtime.h>
#include <cstdint>
#include <cstddef>

typedef unsigned short u16;
typedef __bf16 bf16x8 __attribute__((ext_vector_type(8)));
typedef float f32x4 __attribute__((ext_vector_type(4)));
typedef unsigned short u16x8 __attribute__((ext_vector_type(8)));

#define NB   256
#define MAXN 128
#define MAXE 256
#define MAXC 64
#define HD   256
#define NLAYER 4
#define PN 131072
#define PE 98304
#define QE 131072
#define QC 65536
#define MN (NB*MAXN)   /* 32768 node rows  */
#define ME (NB*MAXE)   /* 65536 edge rows  */
#define MC (NB*MAXC)   /* 16384 cell rows  */

// CSR segment bases in the concatenated histogram/offset arrays
#define SEG_N  0
#define SEG_E  (MN)
#define SEG_EB (MN + ME)
#define SEG_CB (MN + 2*ME)
#define HTOT   (MN + 2*ME + MC)      /* 229376, divisible by 1024 */
#define UPTOT  (PN + PE)             /* csrBd global-index base   */

__device__ __forceinline__ float bf2f(u16 u){
  union{unsigned int i; float f;} x; x.i = ((unsigned int)u) << 16; return x.f;
}
__device__ __forceinline__ u16 f2bf(float f){
  union{float f; unsigned int i;} x; x.f = f;
  unsigned int r = x.i + 0x7fffu + ((x.i >> 16) & 1u);
  return (u16)(r >> 16);
}
__device__ __forceinline__ f32x4 MFMA(bf16x8 a, bf16x8 b, f32x4 c){
  return __builtin_amdgcn_mfma_f32_16x16x32_bf16(a, b, c, 0, 0, 0);
}
// async global->LDS, 16B per lane; lds base wave-uniform (lane*16 implicit)
__device__ __forceinline__ void gl_lds16(const u16* g, u16* l){
  __builtin_amdgcn_global_load_lds(
      (const __attribute__((address_space(1))) unsigned int*)g,
      (__attribute__((address_space(3))) unsigned int*)l, 16, 0, 0);
}

// ---------------- dtype sniff (bf16 vs f32 input buffers)
__global__ void detect_dtype(const u16* __restrict__ x, int* __restrict__ flag){
  if(threadIdx.x == 0 && blockIdx.x == 0){
    int cnt = 0;
    for(int i = 0; i < 64; i++){
      int e = (x[i] >> 7) & 0xFF;
      if(e >= 118 && e <= 136) cnt++;
    }
    *flag = (cnt >= 50) ? 1 : 0;   // 1 = bf16, 0 = f32
  }
}

// ---------------- conv helper: one 8-elem unit at offset i of span (s,d,n)
__device__ __forceinline__ void convSpan(const void* s, u16* d, long n, long i, int isbf){
  if(i + 8 <= n){
    if(isbf){
      *reinterpret_cast<u16x8*>(d + i) = *reinterpret_cast<const u16x8*>((const u16*)s + i);
    }else{
      const float* sp = (const float*)s + i;
      float4 a = *reinterpret_cast<const float4*>(sp);
      float4 b = *reinterpret_cast<const float4*>(sp + 4);
      u16x8 o;
      o[0]=f2bf(a.x); o[1]=f2bf(a.y); o[2]=f2bf(a.z); o[3]=f2bf(a.w);
      o[4]=f2bf(b.x); o[5]=f2bf(b.y); o[6]=f2bf(b.z); o[7]=f2bf(b.w);
      *reinterpret_cast<u16x8*>(d + i) = o;
    }
  }else{
    for(long e = i; e < n; e++)
      d[e] = isbf ? ((const u16*)s)[e] : f2bf(((const float*)s)[e]);
  }
}

// ---------------- fused 3-target feature conversion (n/e/c shapes fixed)
__global__ __launch_bounds__(256) void conv3(const void* __restrict__ s0, u16* __restrict__ d0,
                                             const void* __restrict__ s1, u16* __restrict__ d1,
                                             const void* __restrict__ s2, u16* __restrict__ d2,
                                             const int* __restrict__ flag){
  const long U0 = (long)MN * HD / 8, U1 = (long)ME * HD / 8, U2 = (long)MC * HD / 8;
  long u = (long)blockIdx.x * 256 + threadIdx.x;
  const int isbf = *flag;
  if(u < U0){ convSpan(s0, d0, (long)MN * HD, u * 8, isbf); return; }
  u -= U0;
  if(u < U1){ convSpan(s1, d1, (long)ME * HD, u * 8, isbf); return; }
  u -= U1;
  if(u < U2) convSpan(s2, d2, (long)MC * HD, u * 8, isbf);
}

// ---------------- fused small-parameter conversion (6 spans)
__global__ __launch_bounds__(256) void conv_params(
    const void* sW1, u16* dW1, const void* sb1, u16* db1,
    const void* sW2, u16* dW2, const void* sb2, u16* db2,
    const void* sbs, u16* dbs, const void* sbp, u16* dbp,
    const int* __restrict__ flag){
  long u = (long)blockIdx.x * 256 + threadIdx.x;
  const int isbf = *flag;
  if(u < 49152){ convSpan(sW1, dW1, 393216, u * 8, isbf); return; } u -= 49152;
  if(u < 192)  { convSpan(sb1, db1, 1536,   u * 8, isbf); return; } u -= 192;
  if(u < 640)  { convSpan(sW2, dW2, 5120,   u * 8, isbf); return; } u -= 640;
  if(u < 2)    { convSpan(sb2, db2, 10,     u * 8, isbf); return; } u -= 2;
  if(u < 384)  { convSpan(sbs, dbs, 3072,   u * 8, isbf); return; } u -= 384;
  if(u < 32)     convSpan(sbp, dbp, 256,    u * 8, isbf);
}

// ---------------- f32 -> bf16 (always f32 source; for pooled)
__global__ __launch_bounds__(256) void conv_f2b(const float* __restrict__ s, u16* __restrict__ d, long n){
  long i = ((long)blockIdx.x * 256 + threadIdx.x) * 8;
  if(i >= n) return;
  float4 a = *reinterpret_cast<const float4*>(s + i);
  float4 b = *reinterpret_cast<const float4*>(s + i + 4);
  u16x8 o;
  o[0]=f2bf(a.x); o[1]=f2bf(a.y); o[2]=f2bf(a.z); o[3]=f2bf(a.w);
  o[4]=f2bf(b.x); o[5]=f2bf(b.y); o[6]=f2bf(b.z); o[7]=f2bf(b.w);
  *reinterpret_cast<u16x8*>(d + i) = o;
}

// ---------------- zero fill
__global__ __launch_bounds__(256) void zero_f4(float* __restrict__ p, long n4){
  long i = (long)blockIdx.x * blockDim.x + threadIdx.x;
  if(i >= n4) return;
  float4 z = {0.f, 0.f, 0.f, 0.f};
  *reinterpret_cast<float4*>(p + i * 4) = z;
}

// ---------------- fused weight transpose: 38 [256,256] slices -> bf16 [n*256+k]
// z<12: Wself, z<20: Wupx, z<28: Wupa, z<36: Wb, z==36: Wp, z==37: Wp_ref
__global__ void wt_all(const void* __restrict__ pSelf, const void* __restrict__ pUpx,
                       const void* __restrict__ pUpa, const void* __restrict__ pB,
                       const void* __restrict__ pP, const void* __restrict__ pPref,
                       u16* __restrict__ wt, const int* __restrict__ flag){
  __shared__ u16 t[16][17];
  int z = blockIdx.z;
  const void* src; int m; u16* dst;
  if(z < 12)      { src = pSelf; m = z;      dst = wt; }
  else if(z < 20) { src = pUpx;  m = z - 12; dst = wt + (size_t)12 * 65536; }
  else if(z < 28) { src = pUpa;  m = z - 20; dst = wt + (size_t)20 * 65536; }
  else if(z < 36) { src = pB;    m = z - 28; dst = wt + (size_t)28 * 65536; }
  else if(z == 36){ src = pP;    m = 0;      dst = wt + (size_t)36 * 65536; }
  else            { src = pPref; m = 0;      dst = wt + (size_t)37 * 65536; }
  int n0 = blockIdx.x * 16, k0 = blockIdx.y * 16;
  size_t sidx = (size_t)m * 65536 + (size_t)(k0 + threadIdx.y) * 256 + n0 + threadIdx.x;
  u16 v = (*flag) ? ((const u16*)src)[sidx] : f2bf(((const float*)src)[sidx]);
  t[threadIdx.y][threadIdx.x] = v;
  __syncthreads();
  dst[(size_t)m * 65536 + (size_t)(n0 + threadIdx.y) * 256 + (k0 + threadIdx.x)] =
      t[threadIdx.x][threadIdx.y];
}

// ---------------- W1 transpose: src bf16 [3][256 k][512 o] -> dst [3][512 o][256 k]
__global__ void w1_transpose(const u16* __restrict__ src, u16* __restrict__ dst){
  __shared__ u16 t[16][17];
  int i = blockIdx.z;
  int o0 = blockIdx.x * 16, k0 = blockIdx.y * 16;
  t[threadIdx.y][threadIdx.x] =
      src[(size_t)i * 131072 + (size_t)(k0 + threadIdx.y) * 512 + o0 + threadIdx.x];
  __syncthreads();
  dst[(size_t)i * 131072 + (size_t)(o0 + threadIdx.y) * 256 + (k0 + threadIdx.x)] =
      t[threadIdx.x][threadIdx.y];
}

// ---------------- dedup boundary incidences (.set(1.0): idempotent)
__global__ void dedup_kernel(const int* __restrict__ bb, const int* __restrict__ bi,
                             const int* __restrict__ bj, unsigned int* __restrict__ mask,
                             unsigned char* __restrict__ valid, int Q, int maxI, int maxJ){
  int q = blockIdx.x * blockDim.x + threadIdx.x;
  if(q >= Q) return;
  int s = (bb[q] * maxI + bi[q]) * maxJ + bj[q];
  unsigned int bit = 1u << (s & 31);
  unsigned int old = atomicOr(&mask[s >> 5], bit);
  valid[q] = (old & bit) ? 0 : 1;
}

// ---------------- fused CSR histogram over all 4 segments
__global__ __launch_bounds__(256) void hist_all(
    const int* __restrict__ nub, const int* __restrict__ nui,
    const int* __restrict__ eub, const int* __restrict__ eui,
    const int* __restrict__ ebb, const int* __restrict__ ebi, const unsigned char* __restrict__ ve,
    const int* __restrict__ cbb, const int* __restrict__ cbi, const unsigned char* __restrict__ vc,
    int* __restrict__ hist){
  int bx = blockIdx.x, t = threadIdx.x;
  if(bx < PN/256){
    int p = bx * 256 + t;
    atomicAdd(&hist[SEG_N + nub[p] * MAXN + nui[p]], 1);
  }else if(bx < PN/256 + PE/256){
    int p = (bx - PN/256) * 256 + t;
    atomicAdd(&hist[SEG_E + eub[p] * MAXE + eui[p]], 1);
  }else if(bx < PN/256 + PE/256 + QE/256){
    int q = (bx - PN/256 - PE/256) * 256 + t;
    if(ve[q]) atomicAdd(&hist[SEG_EB + ebb[q] * MAXE + ebi[q]], 1);
  }else{
    int q = (bx - PN/256 - PE/256 - QE/256) * 256 + t;
    if(vc[q]) atomicAdd(&hist[SEG_CB + cbb[q] * MAXC + cbi[q]], 1);
  }
}

// ---------------- 3-phase exclusive scan over HTOT ints (1024 elems / block)
__global__ __launch_bounds__(256) void scan1(const int* __restrict__ hist, int* __restrict__ bsum){
  __shared__ int s[256];
  int t = threadIdx.x;
  long base = (long)blockIdx.x * 1024 + t * 4;
  int4 v = *reinterpret_cast<const int4*>(hist + base);
  s[t] = v.x + v.y + v.z + v.w;
  __syncthreads();
  for(int st = 128; st > 0; st >>= 1){
    if(t < st) s[t] += s[t + st];
    __syncthreads();
  }
  if(t == 0) bsum[blockIdx.x] = s[0];
}
__global__ __launch_bounds__(256) void scan2(int* __restrict__ bsum, int nb){
  __shared__ int s[256];
  int t = threadIdx.x;
  int v = (t < nb) ? bsum[t] : 0;
  s[t] = v;
  __syncthreads();
  for(int st = 1; st < 256; st <<= 1){
    int u = (t >= st) ? s[t - st] : 0;
    __syncthreads();
    s[t] += u;
    __syncthreads();
  }
  if(t < nb) bsum[t] = s[t] - v;   // exclusive
}
__global__ __launch_bounds__(256) void scan3(const int* __restrict__ hist, const int* __restrict__ bsum,
                                             int* __restrict__ off, int* __restrict__ cur){
  __shared__ int s[256];
  int t = threadIdx.x;
  long base = (long)blockIdx.x * 1024 + t * 4;
  int4 v = *reinterpret_cast<const int4*>(hist + base);
  int sum = v.x + v.y + v.z + v.w;
  s[t] = sum;
  __syncthreads();
  for(int st = 1; st < 256; st <<= 1){
    int u = (t >= st) ? s[t - st] : 0;
    __syncthreads();
    s[t] += u;
    __syncthreads();
  }
  int excl = s[t] - sum + bsum[blockIdx.x];
  int4 o;
  o.x = excl; o.y = o.x + v.x; o.z = o.y + v.y; o.w = o.z + v.z;
  *reinterpret_cast<int4*>(off + base) = o;
  *reinterpret_cast<int4*>(cur + base) = o;
}

// ---------------- fused CSR fill over all 4 segments
__global__ __launch_bounds__(256) void fill_all(
    const int* __restrict__ nub, const int* __restrict__ nui,
    const int* __restrict__ nuj, const int* __restrict__ nue,
    const int* __restrict__ eub, const int* __restrict__ eui,
    const int* __restrict__ euj, const int* __restrict__ euc,
    const int* __restrict__ ebb, const int* __restrict__ ebi,
    const int* __restrict__ ebj, const unsigned char* __restrict__ ve,
    const int* __restrict__ cbb, const int* __restrict__ cbi,
    const int* __restrict__ cbj, const unsigned char* __restrict__ vc,
    int* __restrict__ cur, int2* __restrict__ csrUp, int* __restrict__ csrBd){
  int bx = blockIdx.x, t = threadIdx.x;
  if(bx < PN/256){
    int p = bx * 256 + t; int b = nub[p];
    int pos = atomicAdd(&cur[SEG_N + b * MAXN + nui[p]], 1);
    int2 e; e.x = b * MAXN + nuj[p]; e.y = b * MAXE + nue[p];
    csrUp[pos] = e;
  }else if(bx < PN/256 + PE/256){
    int p = (bx - PN/256) * 256 + t; int b = eub[p];
    int pos = atomicAdd(&cur[SEG_E + b * MAXE + eui[p]], 1);
    int2 e; e.x = b * MAXE + euj[p]; e.y = b * MAXC + euc[p];
    csrUp[pos] = e;
  }else if(bx < PN/256 + PE/256 + QE/256){
    int q = (bx - PN/256 - PE/256) * 256 + t;
    if(!ve[q]) return;
    int b = ebb[q];
    int pos = atomicAdd(&cur[SEG_EB + b * MAXE + ebi[q]], 1);
    csrBd[pos - UPTOT] = b * MAXN + ebj[q];
  }else{
    int q = (bx - PN/256 - PE/256 - QE/256) * 256 + t;
    if(!vc[q]) return;
    int b = cbb[q];
    int pos = atomicAdd(&cur[SEG_CB + b * MAXC + cbi[q]], 1);
    csrBd[pos - UPTOT] = b * MAXE + cbj[q];
  }
}

// ---------------- gather: one wave per receiver row; bf16 ACC store; XCD swizzle
template<int HAS_UP, int HAS_BD>
__global__ __launch_bounds__(256) void gather_k(
    const u16* __restrict__ Y, const u16* __restrict__ Z, const u16* __restrict__ BD,
    const int2* __restrict__ csrUp, const int* __restrict__ csrBd,
    const int* __restrict__ off, const int* __restrict__ deg,
    int upBase, int bdBase, u16* __restrict__ ACC, int rowLo){
  const int nb = gridDim.x;
  int bx = blockIdx.x;
  if((nb & 7) == 0) bx = (bx & 7) * (nb >> 3) + (bx >> 3);   // XCD-contiguous ranges
  const int row = rowLo + bx * 4 + (threadIdx.x >> 6);
  const int lane = threadIdx.x & 63;
  const int c = lane * 4;
  float a0 = 0.f, a1 = 0.f, a2 = 0.f, a3 = 0.f;
  if(HAS_UP){
    int s = off[upBase + row];
    int d = deg[upBase + row];
    for(int k = 0; k < d; k++){
      int2 e = csrUp[s + k];
      const ushort4 y = *reinterpret_cast<const ushort4*>(Y + (size_t)e.x * 256 + c);
      const ushort4 z = *reinterpret_cast<const ushort4*>(Z + (size_t)e.y * 256 + c);
      a0 += fmaxf(bf2f(y.x) + bf2f(z.x), 0.f);
      a1 += fmaxf(bf2f(y.y) + bf2f(z.y), 0.f);
      a2 += fmaxf(bf2f(y.z) + bf2f(z.z), 0.f);
      a3 += fmaxf(bf2f(y.w) + bf2f(z.w), 0.f);
    }
  }
  if(HAS_BD){
    int s = off[bdBase + row] - UPTOT;
    int d = deg[bdBase + row];
    for(int k = 0; k < d; k++){
      int j = csrBd[s + k];
      const ushort4 x = *reinterpret_cast<const ushort4*>(BD + (size_t)j * 256 + c);
      a0 += bf2f(x.x); a1 += bf2f(x.y); a2 += bf2f(x.z); a3 += bf2f(x.w);
    }
  }
  ushort4 o; o.x = f2bf(a0); o.y = f2bf(a1); o.z = f2bf(a2); o.w = f2bf(a3);
  *reinterpret_cast<ushort4*>(ACC + (size_t)(row - rowLo) * 256 + c) = o;
}

// ---------------- LDS-staged bf16 MFMA GEMM, v6b: BK=32, 40 KiB LDS ->
// 4 blocks/CU (4 independent barrier domains vs round-5's 2: latency-bound
// with correlated stalls, Occupancy 16.8%, no pipe >24%). Counted-vmcnt
// depth-2 pipeline: 5 loads/wave/tile, steady vmcnt(5), drain only at last
// tile. SWIZZLE FIX vs v6: at 64B row stride banks wrap every 2 rows, so
// the XOR key must be row bits 2-3 (csw = lchk ^ ((lrow>>2)&3), read key
// rsw = (r>>2)&3) -- row bits 0-1 (v6) put lanes r,r+4,r+8,r+12 on the
// same bank (4-way conflict). With bits 2-3: each 16-lane phase is 2-way
// (free), all 64 slots of a 16-row stripe read exactly once. Pre-swizzled
// global source matches global_load_lds's linear dest (both-sides rule).
// Operand-swapped MFMA -> ushort4 8B epilogue stores. 3-way segmented grid.
// MODE 0: C = P@Q.
// MODE 2: C = relu(P@Q + ACCbf + bias), C may alias P.   (single segment)
// MODE 3: C = P@S1 + Q@S2  (P=x, Q=ref, shared weights). C may alias Q.
template<int MODE>
__global__ __launch_bounds__(256) void gemm_k(
    const u16* P0, const u16* Q0, u16* C0, int n0,
    const u16* P1, const u16* Q1, u16* C1, int n1,
    const u16* P2, const u16* Q2, u16* C2,
    const u16* __restrict__ S1, const u16* __restrict__ S2,
    const u16* __restrict__ ACC, const u16* __restrict__ bias){
  __shared__ u16 lA[2][64 * 32];    // [buf][row][k-chunk swizzled]   4 KiB/buf
  __shared__ u16 lB[2][256 * 32];   // [buf][n][k-chunk swizzled]    16 KiB/buf
  int bx = blockIdx.x;
  const u16* P = P0; const u16* Q = Q0; u16* C = C0;
  if(bx >= n0 + n1){ bx -= n0 + n1; P = P2; Q = Q2; C = C2; }
  else if(bx >= n0){ bx -= n0;      P = P1; Q = Q1; C = C1; }
  const int t = threadIdx.x;
  const int lane = t & 63, wv = t >> 6;   // 4 waves, 1 x 4 wave grid
  const int wn = wv;                       // each wave: 64 rows x 64 cols
  const int r = lane & 15, q = lane >> 4;  // q in 0..3 = k-chunk of the fragment
  const int rsw = (r >> 2) & 3;            // read-side XOR key (row bits 2-3)
  const size_t m0 = (size_t)bx * 64;
  const int lrow = lane >> 2, lchk = lane & 3;   // 16 rows x 4 chunks per gl_lds16
  const int csw = lchk ^ ((lrow >> 2) & 3);      // source chunk pre-swizzle

  f32x4 acc[4][4];
#pragma unroll
  for(int i = 0; i < 4; i++)
#pragma unroll
    for(int j = 0; j < 4; j++) acc[i][j] = {0.f, 0.f, 0.f, 0.f};

  const int NT = (MODE == 3) ? 16 : 8;     // tiles: (src, k0) flattened

  auto stage = [&](int tt, int buf){
    const u16* Ap = (MODE == 3) ? ((tt >= 8) ? Q : P) : P;
    const u16* Wp = (MODE == 3) ? ((tt >= 8) ? S2 : S1) : Q;
    const int k0 = (tt & 7) * 32;
    // lA: 64 rows; wave wv stages rows [wv*16, wv*16+16) in ONE load
    gl_lds16(Ap + (m0 + wv * 16 + lrow) * 256 + k0 + csw * 8,
             &lA[buf][(wv * 16) * 32]);
    // lB: 256 rows; wave stages 64 rows = 4 loads (16 rows each)
#pragma unroll
    for(int j = 0; j < 4; j++){
      const int n = wv * 64 + j * 16 + lrow;
      gl_lds16(Wp + (size_t)n * 256 + k0 + csw * 8,
               &lB[buf][(wv * 64 + j * 16) * 32]);
    }
  };

  // prologue: depth-2 prefetch (10 loads/wave in flight)
  stage(0, 0);
  stage(1, 1);

#pragma unroll
  for(int tt = 0; tt < NT; tt++){
    const int cur = tt & 1;
    // tile tt landed; tile tt+1 (if any) stays in flight across the barrier
    if(tt < NT - 1) asm volatile("s_waitcnt vmcnt(5)" ::: "memory");
    else            asm volatile("s_waitcnt vmcnt(0)" ::: "memory");
    __builtin_amdgcn_s_barrier();
    __builtin_amdgcn_s_setprio(1);
    {
      bf16x8 af[4], bfr[4];
#pragma unroll
      for(int i = 0; i < 4; i++)
        af[i] = *reinterpret_cast<const bf16x8*>(
            &lA[cur][(i * 16 + r) * 32 + ((q ^ rsw) * 8)]);
#pragma unroll
      for(int j = 0; j < 4; j++)
        bfr[j] = *reinterpret_cast<const bf16x8*>(
            &lB[cur][(wn * 64 + j * 16 + r) * 32 + ((q ^ rsw) * 8)]);
      // operand-swapped: D[row<-n][col<-m]; per thread n = q*4+reg, m = r
#pragma unroll
      for(int i = 0; i < 4; i++)
#pragma unroll
        for(int j = 0; j < 4; j++) acc[i][j] = MFMA(bfr[j], af[i], acc[i][j]);
    }
    __builtin_amdgcn_s_setprio(0);
    __builtin_amdgcn_s_barrier();   // all waves done reading buf cur
    if(tt + 2 < NT) stage(tt + 2, cur);   // refill the consumed buffer
  }

  // epilogue (swapped layout): row = m0 + i*16 + r, col = wn*64 + j*16 + q*4 + reg
#pragma unroll
  for(int i = 0; i < 4; i++){
    const size_t row = m0 + i * 16 + r;
#pragma unroll
    for(int j = 0; j < 4; j++){
      const int col = wn * 64 + j * 16 + q * 4;
      const size_t idx = row * 256 + col;
      f32x4 v = acc[i][j];
      ushort4 o;
      if(MODE == 2){
        const ushort4 a4 = *reinterpret_cast<const ushort4*>(ACC + idx);
        const ushort4 b4 = *reinterpret_cast<const ushort4*>(bias + col);
        o.x = f2bf(fmaxf(v[0] + bf2f(a4.x) + bf2f(b4.x), 0.f));
        o.y = f2bf(fmaxf(v[1] + bf2f(a4.y) + bf2f(b4.y), 0.f));
        o.z = f2bf(fmaxf(v[2] + bf2f(a4.z) + bf2f(b4.z), 0.f));
        o.w = f2bf(fmaxf(v[3] + bf2f(a4.w) + bf2f(b4.w), 0.f));
      }else{
        o.x = f2bf(v[0]); o.y = f2bf(v[1]); o.z = f2bf(v[2]); o.w = f2bf(v[3]);
      }
      *reinterpret_cast<ushort4*>(C + idx) = o;
    }
  }
}

// ---------------- fused gated pooling reduce over all 3 dims
// grid (NB, 7): y<2 -> nodes (2 chunks), y<6 -> edges (4 chunks), y==6 -> cells.
__global__ __launch_bounds__(256) void pool_all(
    const u16* __restrict__ Gn, const u16* __restrict__ Ge, const u16* __restrict__ Gc,
    const u16* __restrict__ bpv,
    const u16* __restrict__ Xn, const u16* __restrict__ Xe, const u16* __restrict__ Xc,
    float* __restrict__ pooled){
  int b = blockIdx.x, h = threadIdx.x, y = blockIdx.y;
  const u16 *G, *X; float* out; int maxR, r0;
  if(y < 2)      { G = Gn; X = Xn; out = pooled;                    maxR = MAXN; r0 = y * 64; }
  else if(y < 6) { G = Ge; X = Xe; out = pooled + (size_t)NB * HD;  maxR = MAXE; r0 = (y - 2) * 64; }
  else           { G = Gc; X = Xc; out = pooled + (size_t)2*NB*HD;  maxR = MAXC; r0 = 0; }
  float bias = bf2f(bpv[h]);
  float acc = 0.f;
  for(int r = r0; r < r0 + 64; r++){
    size_t o = ((size_t)b * maxR + r) * 256 + h;
    float t = bf2f(G[o]) + bias;
    float w = 1.f / (1.f + __expf(-t));
    acc += w * bf2f(X[o]);
  }
  atomicAdd(&out[b * 256 + h], acc);
}

// ---------------- readout1 as MFMA GEMM (swapped-operand layout)
__global__ __launch_bounds__(512) void readout1_mfma(const u16* __restrict__ Ab,
                                                     const u16* __restrict__ W1t,
                                                     const u16* __restrict__ b1,
                                                     float* __restrict__ hbuf){
  __shared__ u16 lA[2][128 * 64];
  __shared__ u16 lB[2][256 * 64];
  const int t = threadIdx.x;
  const int lane = t & 63, wv = t >> 6;
  const int wm = wv >> 2, wn = wv & 3;      // 2 x 4 wave grid, each 64x64
  const int r = lane & 15, q = lane >> 4;
  const int rsw = r & 7;
  const int b0 = blockIdx.x * 128;
  const int o0 = blockIdx.y * 256;
  const int lrow = lane >> 3, lchk = lane & 7;
  const int csw = lchk ^ lrow;

  f32x4 acc[4][4], facc[4][4];
#pragma unroll
  for(int i = 0; i < 4; i++)
#pragma unroll
    for(int j = 0; j < 4; j++){ acc[i][j] = {0.f,0.f,0.f,0.f}; facc[i][j] = {0.f,0.f,0.f,0.f}; }

  auto stage = [&](int tt, int buf){
    const int ii = tt >> 2, k0 = (tt & 3) * 64;
    const u16* Ap = Ab + (size_t)ii * 65536;
    const u16* Wp = W1t + (size_t)ii * 131072;
#pragma unroll
    for(int i = 0; i < 2; i++){
      const int row = i * 64 + wv * 8 + lrow;
      gl_lds16(Ap + (size_t)(b0 + row) * 256 + k0 + csw * 8, &lA[buf][(i * 64 + wv * 8) * 64]);
    }
#pragma unroll
    for(int j = 0; j < 4; j++){
      const int n = j * 64 + wv * 8 + lrow;
      gl_lds16(Wp + (size_t)(o0 + n) * 256 + k0 + csw * 8, &lB[buf][(j * 64 + wv * 8) * 64]);
    }
  };

  stage(0, 0);
  stage(1, 1);

#pragma unroll
  for(int tt = 0; tt < 12; tt++){
    const int cur = tt & 1;
    if(tt < 11) asm volatile("s_waitcnt vmcnt(6)" ::: "memory");
    else        asm volatile("s_waitcnt vmcnt(0)" ::: "memory");
    __builtin_amdgcn_s_barrier();
#pragma unroll
    for(int ks = 0; ks < 2; ks++){
      bf16x8 af[4], bfr[4];
#pragma unroll
      for(int i = 0; i < 4; i++)
        af[i] = *reinterpret_cast<const bf16x8*>(
            &lA[cur][(wm * 64 + i * 16 + r) * 64 + (((ks * 4 + q) ^ rsw) * 8)]);
#pragma unroll
      for(int j = 0; j < 4; j++)
        bfr[j] = *reinterpret_cast<const bf16x8*>(
            &lB[cur][(wn * 64 + j * 16 + r) * 64 + (((ks * 4 + q) ^ rsw) * 8)]);
#pragma unroll
      for(int i = 0; i < 4; i++)
#pragma unroll
        for(int j = 0; j < 4; j++) acc[i][j] = MFMA(bfr[j], af[i], acc[i][j]);
    }
    if((tt & 3) == 3){   // i boundary: relu-flush into facc (registers only)
      const int ib = tt >> 2;
#pragma unroll
      for(int i = 0; i < 4; i++)
#pragma unroll
        for(int j = 0; j < 4; j++){
          const int col = o0 + wn * 64 + j * 16 + q * 4;
          const ushort4 b4 = *reinterpret_cast<const ushort4*>(b1 + ib * 512 + col);
          facc[i][j][0] += fmaxf(acc[i][j][0] + bf2f(b4.x), 0.f);
          facc[i][j][1] += fmaxf(acc[i][j][1] + bf2f(b4.y), 0.f);
          facc[i][j][2] += fmaxf(acc[i][j][2] + bf2f(b4.z), 0.f);
          facc[i][j][3] += fmaxf(acc[i][j][3] + bf2f(b4.w), 0.f);
          acc[i][j] = {0.f, 0.f, 0.f, 0.f};
        }
    }
    __builtin_amdgcn_s_barrier();
    if(tt + 2 < 12) stage(tt + 2, cur);
  }

  // swapped layout: row = b0 + wm*64 + i*16 + r, col = o0 + wn*64 + j*16 + q*4
#pragma unroll
  for(int i = 0; i < 4; i++){
    const int row = b0 + wm * 64 + i * 16 + r;
#pragma unroll
    for(int j = 0; j < 4; j++){
      const int col = o0 + wn * 64 + j * 16 + q * 4;
      *reinterpret_cast<f32x4*>(hbuf + (size_t)row * 512 + col) = facc[i][j];
    }
  }
}

// ---------------- out = h @ W2 + b2 (dtype-matched store)
__global__ __launch_bounds__(64) void readout2(const float* __restrict__ hbuf, const u16* __restrict__ W2,
                                               const u16* __restrict__ b2, void* __restrict__ out,
                                               const int* __restrict__ flag){
  int b = blockIdx.x, o = threadIdx.x;
  if(o >= 10) return;
  float a = bf2f(b2[o]);
  for(int k = 0; k < 512; k++) a += hbuf[(size_t)b * 512 + k] * bf2f(W2[k * 10 + o]);
  if(*flag) ((u16*)out)[b * 10 + o] = f2bf(a);
  else      ((float*)out)[b * 10 + o] = a;
}

extern "C" void kernel_launch(void* const* d_in, const int* in_sizes, int n_in,
                              void* d_out, int out_size, void* d_ws, size_t ws_size,
                              hipStream_t stream){
  const void* x_n = d_in[0];
  const void* x_e = d_in[1];
  const void* x_c = d_in[2];
  const int* n_up_b = (const int*)d_in[3];
  const int* n_up_i = (const int*)d_in[4];
  const int* n_up_j = (const int*)d_in[5];
  const int* n_up_e = (const int*)d_in[6];
  const int* e_up_b = (const int*)d_in[7];
  const int* e_up_i = (const int*)d_in[8];
  const int* e_up_j = (const int*)d_in[9];
  const int* e_up_c = (const int*)d_in[10];
  const int* eb_b = (const int*)d_in[11];
  const int* eb_i = (const int*)d_in[12];
  const int* eb_j = (const int*)d_in[13];
  const int* cb_b = (const int*)d_in[14];
  const int* cb_i = (const int*)d_in[15];
  const int* cb_j = (const int*)d_in[16];

  // ---- workspace carve-up (~174 MiB)
  char* base = (char*)d_ws; size_t off0 = 0;
  auto alloc = [&](size_t n)->char*{ char* p = base + off0; off0 = (off0 + n + 255) & ~(size_t)255; return p; };
  u16* xn = (u16*)alloc((size_t)MN * HD * 2);
  u16* xe = (u16*)alloc((size_t)ME * HD * 2);
  u16* xc = (u16*)alloc((size_t)MC * HD * 2);
  u16* BIG1 = (u16*)alloc((size_t)ME * HD * 2);      // Ze/BDe/Ye staging
  u16* SMa  = (u16*)alloc((size_t)MN * HD * 2);      // Yn then Zc; pool: REFn/Gn
  u16* SMb  = (u16*)alloc((size_t)MN * HD * 2);      // BDn; pool: REFc/Gc
  u16* ACC  = (u16*)alloc((size_t)ME * HD * 2);      // full-width bf16 gather acc; pool: REFe/Ge
  u16* wt = (u16*)alloc((size_t)38 * 65536 * 2);
  unsigned int* mask_e = (unsigned int*)alloc((size_t)NB * MAXE * MAXN / 8);  // dead after dedup -> params
  unsigned int* mask_c = (unsigned int*)alloc((size_t)NB * MAXC * MAXE / 8);
  unsigned char* valid_e = (unsigned char*)alloc(QE);
  unsigned char* valid_c = (unsigned char*)alloc(QC);
  float* pooled = (float*)alloc((size_t)3 * NB * HD * 4);   // also aliased as scan cursor
  float* hbuf   = (float*)alloc((size_t)NB * 512 * 4);
  int* flag     = (int*)alloc(256);
  int2* csrUp   = (int2*)alloc((size_t)UPTOT * 8);
  int* csrBd    = (int*)alloc((size_t)(QE + QC) * 4);
  int* hist     = (int*)alloc((size_t)HTOT * 4);
  int* offA     = (int*)alloc((size_t)HTOT * 4);
  int* bsum     = (int*)alloc(1024);
  u16* W1t      = (u16*)alloc((size_t)3 * 512 * 256 * 2);   // transposed W1 for readout1
  u16* pooledb  = (u16*)alloc((size_t)3 * NB * HD * 2);     // bf16 pooled for readout1_mfma
  int* cur      = (int*)pooled;   // scan cursor; pooled dead until pooling

  u16* wtSelf = wt;
  u16* wtUpx  = wt + (size_t)12 * 65536;
  u16* wtUpa  = wt + (size_t)20 * 65536;
  u16* wtB    = wt + (size_t)28 * 65536;
  u16* wtP    = wt + (size_t)36 * 65536;
  u16* wtPref = wt + (size_t)37 * 65536;

  // small converted params in mask_e's 1 MiB (dead after dedup)
  u16* W1c = (u16*)mask_e;
  u16* b1c = W1c + 393216;
  u16* W2c = b1c + 1536;
  u16* b2c = W2c + 5120;
  u16* bsc = b2c + 16;
  u16* bpc = bsc + 3072;

  // ---- prologue
  detect_dtype<<<1, 64, 0, stream>>>((const u16*)x_n, flag);
  // masks are contiguous allocations: one zero pass (1.5 MiB)
  zero_f4<<<(98304 + 255)/256, 256, 0, stream>>>((float*)mask_e, 98304);
  dedup_kernel<<<QE/256, 256, 0, stream>>>(eb_b, eb_i, eb_j, mask_e, valid_e, QE, MAXE, MAXN);
  dedup_kernel<<<QC/256, 256, 0, stream>>>(cb_b, cb_i, cb_j, mask_c, valid_c, QC, MAXC, MAXE);

  wt_all<<<dim3(16,16,38), dim3(16,16), 0, stream>>>(d_in[17], d_in[19], d_in[20],
                                                     d_in[21], d_in[22], d_in[23], wt, flag);
  conv3<<<14336, 256, 0, stream>>>(x_n, xn, x_e, xe, x_c, xc, flag);
  conv_params<<<197, 256, 0, stream>>>(d_in[25], W1c, d_in[26], b1c, d_in[27], W2c,
                                       d_in[28], b2c, d_in[18], bsc, d_in[24], bpc, flag);
  w1_transpose<<<dim3(32,16,3), dim3(16,16), 0, stream>>>(W1c, W1t);

  // ---- CSR build (histogram -> scan -> fill), fused
  zero_f4<<<(HTOT/4 + 255)/256, 256, 0, stream>>>((float*)hist, HTOT/4);
  hist_all<<<PN/256 + PE/256 + QE/256 + QC/256, 256, 0, stream>>>(
      n_up_b, n_up_i, e_up_b, e_up_i, eb_b, eb_i, valid_e, cb_b, cb_i, valid_c, hist);
  scan1<<<HTOT/1024, 256, 0, stream>>>(hist, bsum);
  scan2<<<1, 256, 0, stream>>>(bsum, HTOT/1024);
  scan3<<<HTOT/1024, 256, 0, stream>>>(hist, bsum, offA, cur);
  fill_all<<<PN/256 + PE/256 + QE/256 + QC/256, 256, 0, stream>>>(
      n_up_b, n_up_i, n_up_j, n_up_e, e_up_b, e_up_i, e_up_j, e_up_c,
      eb_b, eb_i, eb_j, valid_e, cb_b, cb_i, cb_j, valid_c, cur, csrUp, csrBd);

  // ---- layers (9 dispatches each)
  for(int l = 0; l < NLAYER; l++){
    const u16* Wupx0 = wtUpx + (size_t)(l*2+0) * 65536;
    const u16* Wupx1 = wtUpx + (size_t)(l*2+1) * 65536;
    const u16* Wupa0 = wtUpa + (size_t)(l*2+0) * 65536;
    const u16* Wupa1 = wtUpa + (size_t)(l*2+1) * 65536;
    const u16* Wb0   = wtB   + (size_t)(l*2+0) * 65536;
    const u16* Wb1   = wtB   + (size_t)(l*2+1) * 65536;
    const u16* Ws0   = wtSelf + (size_t)(l*3+0) * 65536;
    const u16* Ws1   = wtSelf + (size_t)(l*3+1) * 65536;
    const u16* Ws2   = wtSelf + (size_t)(l*3+2) * 65536;
    const u16* bs0 = bsc + (size_t)(l*3+0) * HD;
    const u16* bs1 = bsc + (size_t)(l*3+1) * HD;
    const u16* bs2 = bsc + (size_t)(l*3+2) * HD;

    // nodes: {Yn(SMa), Ze(BIG1), BDn(SMb)} from OLD xn/xe in ONE dispatch
    gemm_k<0><<<MN/64 + ME/64 + MN/64, 256, 0, stream>>>(
        xn, Wupx0, SMa, MN/64, xe, Wupa0, BIG1, ME/64, xn, Wb0, SMb,
        nullptr, nullptr, nullptr, nullptr);
    gather_k<1,0><<<MN/4, 256, 0, stream>>>(SMa, BIG1, nullptr, csrUp, csrBd,
                                            offA, hist, SEG_N, 0, ACC, 0);
    gemm_k<2><<<MN/64, 256, 0, stream>>>(xn, Ws0, xn, MN/64, xn, Ws0, xn, 0, xn, Ws0, xn,
                                         nullptr, nullptr, ACC, bs0);

    // cells: {Zc(SMa, held for edges), BDe(BIG1)} in ONE dispatch
    gemm_k<0><<<MC/64 + ME/64, 256, 0, stream>>>(
        xc, Wupa1, SMa, MC/64, xe, Wb1, BIG1, ME/64, xc, Wupa1, SMa,
        nullptr, nullptr, nullptr, nullptr);
    gather_k<0,1><<<MC/4, 256, 0, stream>>>(nullptr, nullptr, BIG1, csrUp, csrBd,
                                            offA, hist, 0, SEG_CB, ACC, 0);
    gemm_k<2><<<MC/64, 256, 0, stream>>>(xc, Ws2, xc, MC/64, xc, Ws2, xc, 0, xc, Ws2, xc,
                                         nullptr, nullptr, ACC, bs2);

    // edges: Ye(BIG1) from OLD xe; full-width gather + fused self
    gemm_k<0><<<ME/64, 256, 0, stream>>>(
        xe, Wupx1, BIG1, ME/64, xe, Wupx1, BIG1, 0, xe, Wupx1, BIG1,
        nullptr, nullptr, nullptr, nullptr);
    gather_k<1,1><<<ME/4, 256, 0, stream>>>(BIG1, SMa, SMb, csrUp, csrBd,
                                            offA, hist, SEG_E, SEG_EB, ACC, 0);
    gemm_k<2><<<ME/64, 256, 0, stream>>>(xe, Ws1, xe, ME/64, xe, Ws1, xe, 0, xe, Ws1, xe,
                                         nullptr, nullptr, ACC, bs1);
  }

  // ---- gated pooling: REFs into SMa/ACC/SMb, ONE segmented dual-A GEMM
  // (G aliases REF: per-block A2 rows fully staged before C rows written),
  // then one fused pool_all.
  conv3<<<14336, 256, 0, stream>>>(x_n, SMa, x_e, ACC, x_c, SMb, flag);
  {
    long np4 = (long)3 * NB * HD / 4;
    zero_f4<<<(int)((np4 + 255)/256), 256, 0, stream>>>(pooled, np4);
  }
  gemm_k<3><<<MN/64 + ME/64 + MC/64, 256, 0, stream>>>(
      xn, SMa, SMa, MN/64, xe, ACC, ACC, ME/64, xc, SMb, SMb,
      wtP, wtPref, nullptr, nullptr);
  pool_all<<<dim3(NB, 7), 256, 0, stream>>>(SMa, ACC, SMb, bpc, xn, xe, xc, pooled);

  // ---- readout
  conv_f2b<<<96, 256, 0, stream>>>(pooled, pooledb, (long)3 * NB * HD);
  readout1_mfma<<<dim3(2,2), 512, 0, stream>>>(pooledb, W1t, b1c, hbuf);
  readout2<<<NB, 64, 0, stream>>>(hbuf, W2c, b2c, d_out, flag);
}

// Round 8
// 1324.642 us; speedup vs baseline: 1.0120x; 1.0120x over previous
//
#include <hip/hip_runtime.h>
#include <cstdint>
#include <cstddef>

typedef unsigned short u16;
typedef __bf16 bf16x8 __attribute__((ext_vector_type(8)));
typedef float f32x4 __attribute__((ext_vector_type(4)));
typedef unsigned short u16x8 __attribute__((ext_vector_type(8)));

#define NB   256
#define MAXN 128
#define MAXE 256
#define MAXC 64
#define HD   256
#define NLAYER 4
#define PN 131072
#define PE 98304
#define QE 131072
#define QC 65536
#define MN (NB*MAXN)   /* 32768 node rows  */
#define ME (NB*MAXE)   /* 65536 edge rows  */
#define MC (NB*MAXC)   /* 16384 cell rows  */

// CSR segment bases in the concatenated histogram/offset arrays
#define SEG_N  0
#define SEG_E  (MN)
#define SEG_EB (MN + ME)
#define SEG_CB (MN + 2*ME)
#define HTOT   (MN + 2*ME + MC)      /* 229376, divisible by 1024 */
#define UPTOT  (PN + PE)             /* csrBd global-index base   */

__device__ __forceinline__ float bf2f(u16 u){
  union{unsigned int i; float f;} x; x.i = ((unsigned int)u) << 16; return x.f;
}
__device__ __forceinline__ u16 f2bf(float f){
  union{float f; unsigned int i;} x; x.f = f;
  unsigned int r = x.i + 0x7fffu + ((x.i >> 16) & 1u);
  return (u16)(r >> 16);
}
__device__ __forceinline__ f32x4 MFMA(bf16x8 a, bf16x8 b, f32x4 c){
  return __builtin_amdgcn_mfma_f32_16x16x32_bf16(a, b, c, 0, 0, 0);
}
// async global->LDS, 16B per lane; lds base wave-uniform (lane*16 implicit)
__device__ __forceinline__ void gl_lds16(const u16* g, u16* l){
  __builtin_amdgcn_global_load_lds(
      (const __attribute__((address_space(1))) unsigned int*)g,
      (__attribute__((address_space(3))) unsigned int*)l, 16, 0, 0);
}

// ---------------- dtype sniff (bf16 vs f32 input buffers)
__global__ void detect_dtype(const u16* __restrict__ x, int* __restrict__ flag){
  if(threadIdx.x == 0 && blockIdx.x == 0){
    int cnt = 0;
    for(int i = 0; i < 64; i++){
      int e = (x[i] >> 7) & 0xFF;
      if(e >= 118 && e <= 136) cnt++;
    }
    *flag = (cnt >= 50) ? 1 : 0;   // 1 = bf16, 0 = f32
  }
}

// ---------------- conv helper: one 8-elem unit at offset i of span (s,d,n)
__device__ __forceinline__ void convSpan(const void* s, u16* d, long n, long i, int isbf){
  if(i + 8 <= n){
    if(isbf){
      *reinterpret_cast<u16x8*>(d + i) = *reinterpret_cast<const u16x8*>((const u16*)s + i);
    }else{
      const float* sp = (const float*)s + i;
      float4 a = *reinterpret_cast<const float4*>(sp);
      float4 b = *reinterpret_cast<const float4*>(sp + 4);
      u16x8 o;
      o[0]=f2bf(a.x); o[1]=f2bf(a.y); o[2]=f2bf(a.z); o[3]=f2bf(a.w);
      o[4]=f2bf(b.x); o[5]=f2bf(b.y); o[6]=f2bf(b.z); o[7]=f2bf(b.w);
      *reinterpret_cast<u16x8*>(d + i) = o;
    }
  }else{
    for(long e = i; e < n; e++)
      d[e] = isbf ? ((const u16*)s)[e] : f2bf(((const float*)s)[e]);
  }
}

// ---------------- fused 3-target feature conversion (n/e/c shapes fixed)
__global__ __launch_bounds__(256) void conv3(const void* __restrict__ s0, u16* __restrict__ d0,
                                             const void* __restrict__ s1, u16* __restrict__ d1,
                                             const void* __restrict__ s2, u16* __restrict__ d2,
                                             const int* __restrict__ flag){
  const long U0 = (long)MN * HD / 8, U1 = (long)ME * HD / 8, U2 = (long)MC * HD / 8;
  long u = (long)blockIdx.x * 256 + threadIdx.x;
  const int isbf = *flag;
  if(u < U0){ convSpan(s0, d0, (long)MN * HD, u * 8, isbf); return; }
  u -= U0;
  if(u < U1){ convSpan(s1, d1, (long)ME * HD, u * 8, isbf); return; }
  u -= U1;
  if(u < U2) convSpan(s2, d2, (long)MC * HD, u * 8, isbf);
}

// ---------------- fused small-parameter conversion (6 spans)
__global__ __launch_bounds__(256) void conv_params(
    const void* sW1, u16* dW1, const void* sb1, u16* db1,
    const void* sW2, u16* dW2, const void* sb2, u16* db2,
    const void* sbs, u16* dbs, const void* sbp, u16* dbp,
    const int* __restrict__ flag){
  long u = (long)blockIdx.x * 256 + threadIdx.x;
  const int isbf = *flag;
  if(u < 49152){ convSpan(sW1, dW1, 393216, u * 8, isbf); return; } u -= 49152;
  if(u < 192)  { convSpan(sb1, db1, 1536,   u * 8, isbf); return; } u -= 192;
  if(u < 640)  { convSpan(sW2, dW2, 5120,   u * 8, isbf); return; } u -= 640;
  if(u < 2)    { convSpan(sb2, db2, 10,     u * 8, isbf); return; } u -= 2;
  if(u < 384)  { convSpan(sbs, dbs, 3072,   u * 8, isbf); return; } u -= 384;
  if(u < 32)     convSpan(sbp, dbp, 256,    u * 8, isbf);
}

// ---------------- f32 -> bf16 (always f32 source; for pooled)
__global__ __launch_bounds__(256) void conv_f2b(const float* __restrict__ s, u16* __restrict__ d, long n){
  long i = ((long)blockIdx.x * 256 + threadIdx.x) * 8;
  if(i >= n) return;
  float4 a = *reinterpret_cast<const float4*>(s + i);
  float4 b = *reinterpret_cast<const float4*>(s + i + 4);
  u16x8 o;
  o[0]=f2bf(a.x); o[1]=f2bf(a.y); o[2]=f2bf(a.z); o[3]=f2bf(a.w);
  o[4]=f2bf(b.x); o[5]=f2bf(b.y); o[6]=f2bf(b.z); o[7]=f2bf(b.w);
  *reinterpret_cast<u16x8*>(d + i) = o;
}

// ---------------- zero fill
__global__ __launch_bounds__(256) void zero_f4(float* __restrict__ p, long n4){
  long i = (long)blockIdx.x * blockDim.x + threadIdx.x;
  if(i >= n4) return;
  float4 z = {0.f, 0.f, 0.f, 0.f};
  *reinterpret_cast<float4*>(p + i * 4) = z;
}

// ---------------- fused weight transpose: 38 [256,256] slices -> bf16 [n*256+k]
// z<12: Wself, z<20: Wupx, z<28: Wupa, z<36: Wb, z==36: Wp, z==37: Wp_ref
__global__ void wt_all(const void* __restrict__ pSelf, const void* __restrict__ pUpx,
                       const void* __restrict__ pUpa, const void* __restrict__ pB,
                       const void* __restrict__ pP, const void* __restrict__ pPref,
                       u16* __restrict__ wt, const int* __restrict__ flag){
  __shared__ u16 t[16][17];
  int z = blockIdx.z;
  const void* src; int m; u16* dst;
  if(z < 12)      { src = pSelf; m = z;      dst = wt; }
  else if(z < 20) { src = pUpx;  m = z - 12; dst = wt + (size_t)12 * 65536; }
  else if(z < 28) { src = pUpa;  m = z - 20; dst = wt + (size_t)20 * 65536; }
  else if(z < 36) { src = pB;    m = z - 28; dst = wt + (size_t)28 * 65536; }
  else if(z == 36){ src = pP;    m = 0;      dst = wt + (size_t)36 * 65536; }
  else            { src = pPref; m = 0;      dst = wt + (size_t)37 * 65536; }
  int n0 = blockIdx.x * 16, k0 = blockIdx.y * 16;
  size_t sidx = (size_t)m * 65536 + (size_t)(k0 + threadIdx.y) * 256 + n0 + threadIdx.x;
  u16 v = (*flag) ? ((const u16*)src)[sidx] : f2bf(((const float*)src)[sidx]);
  t[threadIdx.y][threadIdx.x] = v;
  __syncthreads();
  dst[(size_t)m * 65536 + (size_t)(n0 + threadIdx.y) * 256 + (k0 + threadIdx.x)] =
      t[threadIdx.x][threadIdx.y];
}

// ---------------- W1 transpose: src bf16 [3][256 k][512 o] -> dst [3][512 o][256 k]
__global__ void w1_transpose(const u16* __restrict__ src, u16* __restrict__ dst){
  __shared__ u16 t[16][17];
  int i = blockIdx.z;
  int o0 = blockIdx.x * 16, k0 = blockIdx.y * 16;
  t[threadIdx.y][threadIdx.x] =
      src[(size_t)i * 131072 + (size_t)(k0 + threadIdx.y) * 512 + o0 + threadIdx.x];
  __syncthreads();
  dst[(size_t)i * 131072 + (size_t)(o0 + threadIdx.y) * 256 + (k0 + threadIdx.x)] =
      t[threadIdx.x][threadIdx.y];
}

// ---------------- dedup boundary incidences (.set(1.0): idempotent)
__global__ void dedup_kernel(const int* __restrict__ bb, const int* __restrict__ bi,
                             const int* __restrict__ bj, unsigned int* __restrict__ mask,
                             unsigned char* __restrict__ valid, int Q, int maxI, int maxJ){
  int q = blockIdx.x * blockDim.x + threadIdx.x;
  if(q >= Q) return;
  int s = (bb[q] * maxI + bi[q]) * maxJ + bj[q];
  unsigned int bit = 1u << (s & 31);
  unsigned int old = atomicOr(&mask[s >> 5], bit);
  valid[q] = (old & bit) ? 0 : 1;
}

// ---------------- fused CSR histogram over all 4 segments
__global__ __launch_bounds__(256) void hist_all(
    const int* __restrict__ nub, const int* __restrict__ nui,
    const int* __restrict__ eub, const int* __restrict__ eui,
    const int* __restrict__ ebb, const int* __restrict__ ebi, const unsigned char* __restrict__ ve,
    const int* __restrict__ cbb, const int* __restrict__ cbi, const unsigned char* __restrict__ vc,
    int* __restrict__ hist){
  int bx = blockIdx.x, t = threadIdx.x;
  if(bx < PN/256){
    int p = bx * 256 + t;
    atomicAdd(&hist[SEG_N + nub[p] * MAXN + nui[p]], 1);
  }else if(bx < PN/256 + PE/256){
    int p = (bx - PN/256) * 256 + t;
    atomicAdd(&hist[SEG_E + eub[p] * MAXE + eui[p]], 1);
  }else if(bx < PN/256 + PE/256 + QE/256){
    int q = (bx - PN/256 - PE/256) * 256 + t;
    if(ve[q]) atomicAdd(&hist[SEG_EB + ebb[q] * MAXE + ebi[q]], 1);
  }else{
    int q = (bx - PN/256 - PE/256 - QE/256) * 256 + t;
    if(vc[q]) atomicAdd(&hist[SEG_CB + cbb[q] * MAXC + cbi[q]], 1);
  }
}

// ---------------- 3-phase exclusive scan over HTOT ints (1024 elems / block)
__global__ __launch_bounds__(256) void scan1(const int* __restrict__ hist, int* __restrict__ bsum){
  __shared__ int s[256];
  int t = threadIdx.x;
  long base = (long)blockIdx.x * 1024 + t * 4;
  int4 v = *reinterpret_cast<const int4*>(hist + base);
  s[t] = v.x + v.y + v.z + v.w;
  __syncthreads();
  for(int st = 128; st > 0; st >>= 1){
    if(t < st) s[t] += s[t + st];
    __syncthreads();
  }
  if(t == 0) bsum[blockIdx.x] = s[0];
}
__global__ __launch_bounds__(256) void scan2(int* __restrict__ bsum, int nb){
  __shared__ int s[256];
  int t = threadIdx.x;
  int v = (t < nb) ? bsum[t] : 0;
  s[t] = v;
  __syncthreads();
  for(int st = 1; st < 256; st <<= 1){
    int u = (t >= st) ? s[t - st] : 0;
    __syncthreads();
    s[t] += u;
    __syncthreads();
  }
  if(t < nb) bsum[t] = s[t] - v;   // exclusive
}
__global__ __launch_bounds__(256) void scan3(const int* __restrict__ hist, const int* __restrict__ bsum,
                                             int* __restrict__ off, int* __restrict__ cur){
  __shared__ int s[256];
  int t = threadIdx.x;
  long base = (long)blockIdx.x * 1024 + t * 4;
  int4 v = *reinterpret_cast<const int4*>(hist + base);
  int sum = v.x + v.y + v.z + v.w;
  s[t] = sum;
  __syncthreads();
  for(int st = 1; st < 256; st <<= 1){
    int u = (t >= st) ? s[t - st] : 0;
    __syncthreads();
    s[t] += u;
    __syncthreads();
  }
  int excl = s[t] - sum + bsum[blockIdx.x];
  int4 o;
  o.x = excl; o.y = o.x + v.x; o.z = o.y + v.y; o.w = o.z + v.z;
  *reinterpret_cast<int4*>(off + base) = o;
  *reinterpret_cast<int4*>(cur + base) = o;
}

// ---------------- fused CSR fill over all 4 segments
__global__ __launch_bounds__(256) void fill_all(
    const int* __restrict__ nub, const int* __restrict__ nui,
    const int* __restrict__ nuj, const int* __restrict__ nue,
    const int* __restrict__ eub, const int* __restrict__ eui,
    const int* __restrict__ euj, const int* __restrict__ euc,
    const int* __restrict__ ebb, const int* __restrict__ ebi,
    const int* __restrict__ ebj, const unsigned char* __restrict__ ve,
    const int* __restrict__ cbb, const int* __restrict__ cbi,
    const int* __restrict__ cbj, const unsigned char* __restrict__ vc,
    int* __restrict__ cur, int2* __restrict__ csrUp, int* __restrict__ csrBd){
  int bx = blockIdx.x, t = threadIdx.x;
  if(bx < PN/256){
    int p = bx * 256 + t; int b = nub[p];
    int pos = atomicAdd(&cur[SEG_N + b * MAXN + nui[p]], 1);
    int2 e; e.x = b * MAXN + nuj[p]; e.y = b * MAXE + nue[p];
    csrUp[pos] = e;
  }else if(bx < PN/256 + PE/256){
    int p = (bx - PN/256) * 256 + t; int b = eub[p];
    int pos = atomicAdd(&cur[SEG_E + b * MAXE + eui[p]], 1);
    int2 e; e.x = b * MAXE + euj[p]; e.y = b * MAXC + euc[p];
    csrUp[pos] = e;
  }else if(bx < PN/256 + PE/256 + QE/256){
    int q = (bx - PN/256 - PE/256) * 256 + t;
    if(!ve[q]) return;
    int b = ebb[q];
    int pos = atomicAdd(&cur[SEG_EB + b * MAXE + ebi[q]], 1);
    csrBd[pos - UPTOT] = b * MAXN + ebj[q];
  }else{
    int q = (bx - PN/256 - PE/256 - QE/256) * 256 + t;
    if(!vc[q]) return;
    int b = cbb[q];
    int pos = atomicAdd(&cur[SEG_CB + b * MAXC + cbi[q]], 1);
    csrBd[pos - UPTOT] = b * MAXE + cbj[q];
  }
}

// ---------------- gather: one wave per receiver row; bf16 ACC store; XCD swizzle
template<int HAS_UP, int HAS_BD>
__global__ __launch_bounds__(256) void gather_k(
    const u16* __restrict__ Y, const u16* __restrict__ Z, const u16* __restrict__ BD,
    const int2* __restrict__ csrUp, const int* __restrict__ csrBd,
    const int* __restrict__ off, const int* __restrict__ deg,
    int upBase, int bdBase, u16* __restrict__ ACC, int rowLo){
  const int nb = gridDim.x;
  int bx = blockIdx.x;
  if((nb & 7) == 0) bx = (bx & 7) * (nb >> 3) + (bx >> 3);   // XCD-contiguous ranges
  const int row = rowLo + bx * 4 + (threadIdx.x >> 6);
  const int lane = threadIdx.x & 63;
  const int c = lane * 4;
  float a0 = 0.f, a1 = 0.f, a2 = 0.f, a3 = 0.f;
  if(HAS_UP){
    int s = off[upBase + row];
    int d = deg[upBase + row];
    for(int k = 0; k < d; k++){
      int2 e = csrUp[s + k];
      const ushort4 y = *reinterpret_cast<const ushort4*>(Y + (size_t)e.x * 256 + c);
      const ushort4 z = *reinterpret_cast<const ushort4*>(Z + (size_t)e.y * 256 + c);
      a0 += fmaxf(bf2f(y.x) + bf2f(z.x), 0.f);
      a1 += fmaxf(bf2f(y.y) + bf2f(z.y), 0.f);
      a2 += fmaxf(bf2f(y.z) + bf2f(z.z), 0.f);
      a3 += fmaxf(bf2f(y.w) + bf2f(z.w), 0.f);
    }
  }
  if(HAS_BD){
    int s = off[bdBase + row] - UPTOT;
    int d = deg[bdBase + row];
    for(int k = 0; k < d; k++){
      int j = csrBd[s + k];
      const ushort4 x = *reinterpret_cast<const ushort4*>(BD + (size_t)j * 256 + c);
      a0 += bf2f(x.x); a1 += bf2f(x.y); a2 += bf2f(x.z); a3 += bf2f(x.w);
    }
  }
  ushort4 o; o.x = f2bf(a0); o.y = f2bf(a1); o.z = f2bf(a2); o.w = f2bf(a3);
  *reinterpret_cast<ushort4*>(ACC + (size_t)(row - rowLo) * 256 + c) = o;
}

// ---------------- LDS-staged bf16 MFMA GEMM, v6c: BK=32, 40 KiB LDS ->
// 4 blocks/CU. Counted-vmcnt depth-2 pipeline: 5 loads/wave/tile, steady
// vmcnt(5), drain only at last tile.
// SWIZZLE FIX vs round 7 (measured 3.67M conflicts = exactly 7 extra
// cycles per ds_read_b128): HW serves a wave64 b128 in 8 phases of 8
// consecutive lanes; a phase is conflict-free iff its 8 lanes tile all
// 32 banks. At 64B row stride, bank base = 16*(r&1) + 4*chunk, and a
// phase spans 8 consecutive r -- so the XOR key must take all 4 values
// on {0,2,4,6} and on {1,3,5,7}: key = (r>>1)&3. Round 7's (r>>2)&3 was
// constant over r..r+3 -> every (r&1,chunk) pair doubled -> 2-way
// conflict each phase. Bijectivity: all row bases (i*16, wv*16, wv*64+
// j*16) are == 0 mod 4 after >>1, so stage key (lrow>>1)&3 == read key
// (r>>1)&3 for every tile. Pre-swizzled global source + linear
// global_load_lds dest + swizzled read (both-sides rule).
// Operand-swapped MFMA -> ushort4 8B epilogue stores. 3-way segmented grid.
// MODE 0: C = P@Q.
// MODE 2: C = relu(P@Q + ACCbf + bias), C may alias P.   (single segment)
// MODE 3: C = P@S1 + Q@S2  (P=x, Q=ref, shared weights). C may alias Q.
template<int MODE>
__global__ __launch_bounds__(256) void gemm_k(
    const u16* P0, const u16* Q0, u16* C0, int n0,
    const u16* P1, const u16* Q1, u16* C1, int n1,
    const u16* P2, const u16* Q2, u16* C2,
    const u16* __restrict__ S1, const u16* __restrict__ S2,
    const u16* __restrict__ ACC, const u16* __restrict__ bias){
  __shared__ u16 lA[2][64 * 32];    // [buf][row][k-chunk swizzled]   4 KiB/buf
  __shared__ u16 lB[2][256 * 32];   // [buf][n][k-chunk swizzled]    16 KiB/buf
  int bx = blockIdx.x;
  const u16* P = P0; const u16* Q = Q0; u16* C = C0;
  if(bx >= n0 + n1){ bx -= n0 + n1; P = P2; Q = Q2; C = C2; }
  else if(bx >= n0){ bx -= n0;      P = P1; Q = Q1; C = C1; }
  const int t = threadIdx.x;
  const int lane = t & 63, wv = t >> 6;   // 4 waves, 1 x 4 wave grid
  const int wn = wv;                       // each wave: 64 rows x 64 cols
  const int r = lane & 15, q = lane >> 4;  // q in 0..3 = k-chunk of the fragment
  const int rsw = (r >> 1) & 3;            // read-side XOR key (row bits 1-2)
  const size_t m0 = (size_t)bx * 64;
  const int lrow = lane >> 2, lchk = lane & 3;   // 16 rows x 4 chunks per gl_lds16
  const int csw = lchk ^ ((lrow >> 1) & 3);      // source chunk pre-swizzle

  f32x4 acc[4][4];
#pragma unroll
  for(int i = 0; i < 4; i++)
#pragma unroll
    for(int j = 0; j < 4; j++) acc[i][j] = {0.f, 0.f, 0.f, 0.f};

  const int NT = (MODE == 3) ? 16 : 8;     // tiles: (src, k0) flattened

  auto stage = [&](int tt, int buf){
    const u16* Ap = (MODE == 3) ? ((tt >= 8) ? Q : P) : P;
    const u16* Wp = (MODE == 3) ? ((tt >= 8) ? S2 : S1) : Q;
    const int k0 = (tt & 7) * 32;
    // lA: 64 rows; wave wv stages rows [wv*16, wv*16+16) in ONE load
    gl_lds16(Ap + (m0 + wv * 16 + lrow) * 256 + k0 + csw * 8,
             &lA[buf][(wv * 16) * 32]);
    // lB: 256 rows; wave stages 64 rows = 4 loads (16 rows each)
#pragma unroll
    for(int j = 0; j < 4; j++){
      const int n = wv * 64 + j * 16 + lrow;
      gl_lds16(Wp + (size_t)n * 256 + k0 + csw * 8,
               &lB[buf][(wv * 64 + j * 16) * 32]);
    }
  };

  // prologue: depth-2 prefetch (10 loads/wave in flight)
  stage(0, 0);
  stage(1, 1);

#pragma unroll
  for(int tt = 0; tt < NT; tt++){
    const int cur = tt & 1;
    // tile tt landed; tile tt+1 (if any) stays in flight across the barrier
    if(tt < NT - 1) asm volatile("s_waitcnt vmcnt(5)" ::: "memory");
    else            asm volatile("s_waitcnt vmcnt(0)" ::: "memory");
    __builtin_amdgcn_s_barrier();
    __builtin_amdgcn_s_setprio(1);
    {
      bf16x8 af[4], bfr[4];
#pragma unroll
      for(int i = 0; i < 4; i++)
        af[i] = *reinterpret_cast<const bf16x8*>(
            &lA[cur][(i * 16 + r) * 32 + ((q ^ rsw) * 8)]);
#pragma unroll
      for(int j = 0; j < 4; j++)
        bfr[j] = *reinterpret_cast<const bf16x8*>(
            &lB[cur][(wn * 64 + j * 16 + r) * 32 + ((q ^ rsw) * 8)]);
      // operand-swapped: D[row<-n][col<-m]; per thread n = q*4+reg, m = r
#pragma unroll
      for(int i = 0; i < 4; i++)
#pragma unroll
        for(int j = 0; j < 4; j++) acc[i][j] = MFMA(bfr[j], af[i], acc[i][j]);
    }
    __builtin_amdgcn_s_setprio(0);
    __builtin_amdgcn_s_barrier();   // all waves done reading buf cur
    if(tt + 2 < NT) stage(tt + 2, cur);   // refill the consumed buffer
  }

  // epilogue (swapped layout): row = m0 + i*16 + r, col = wn*64 + j*16 + q*4 + reg
#pragma unroll
  for(int i = 0; i < 4; i++){
    const size_t row = m0 + i * 16 + r;
#pragma unroll
    for(int j = 0; j < 4; j++){
      const int col = wn * 64 + j * 16 + q * 4;
      const size_t idx = row * 256 + col;
      f32x4 v = acc[i][j];
      ushort4 o;
      if(MODE == 2){
        const ushort4 a4 = *reinterpret_cast<const ushort4*>(ACC + idx);
        const ushort4 b4 = *reinterpret_cast<const ushort4*>(bias + col);
        o.x = f2bf(fmaxf(v[0] + bf2f(a4.x) + bf2f(b4.x), 0.f));
        o.y = f2bf(fmaxf(v[1] + bf2f(a4.y) + bf2f(b4.y), 0.f));
        o.z = f2bf(fmaxf(v[2] + bf2f(a4.z) + bf2f(b4.z), 0.f));
        o.w = f2bf(fmaxf(v[3] + bf2f(a4.w) + bf2f(b4.w), 0.f));
      }else{
        o.x = f2bf(v[0]); o.y = f2bf(v[1]); o.z = f2bf(v[2]); o.w = f2bf(v[3]);
      }
      *reinterpret_cast<ushort4*>(C + idx) = o;
    }
  }
}

// ---------------- fused gated pooling reduce over all 3 dims
// grid (NB, 7): y<2 -> nodes (2 chunks), y<6 -> edges (4 chunks), y==6 -> cells.
__global__ __launch_bounds__(256) void pool_all(
    const u16* __restrict__ Gn, const u16* __restrict__ Ge, const u16* __restrict__ Gc,
    const u16* __restrict__ bpv,
    const u16* __restrict__ Xn, const u16* __restrict__ Xe, const u16* __restrict__ Xc,
    float* __restrict__ pooled){
  int b = blockIdx.x, h = threadIdx.x, y = blockIdx.y;
  const u16 *G, *X; float* out; int maxR, r0;
  if(y < 2)      { G = Gn; X = Xn; out = pooled;                    maxR = MAXN; r0 = y * 64; }
  else if(y < 6) { G = Ge; X = Xe; out = pooled + (size_t)NB * HD;  maxR = MAXE; r0 = (y - 2) * 64; }
  else           { G = Gc; X = Xc; out = pooled + (size_t)2*NB*HD;  maxR = MAXC; r0 = 0; }
  float bias = bf2f(bpv[h]);
  float acc = 0.f;
  for(int r = r0; r < r0 + 64; r++){
    size_t o = ((size_t)b * maxR + r) * 256 + h;
    float t = bf2f(G[o]) + bias;
    float w = 1.f / (1.f + __expf(-t));
    acc += w * bf2f(X[o]);
  }
  atomicAdd(&out[b * 256 + h], acc);
}

// ---------------- readout1 as MFMA GEMM (swapped-operand layout)
__global__ __launch_bounds__(512) void readout1_mfma(const u16* __restrict__ Ab,
                                                     const u16* __restrict__ W1t,
                                                     const u16* __restrict__ b1,
                                                     float* __restrict__ hbuf){
  __shared__ u16 lA[2][128 * 64];
  __shared__ u16 lB[2][256 * 64];
  const int t = threadIdx.x;
  const int lane = t & 63, wv = t >> 6;
  const int wm = wv >> 2, wn = wv & 3;      // 2 x 4 wave grid, each 64x64
  const int r = lane & 15, q = lane >> 4;
  const int rsw = r & 7;
  const int b0 = blockIdx.x * 128;
  const int o0 = blockIdx.y * 256;
  const int lrow = lane >> 3, lchk = lane & 7;
  const int csw = lchk ^ lrow;

  f32x4 acc[4][4], facc[4][4];
#pragma unroll
  for(int i = 0; i < 4; i++)
#pragma unroll
    for(int j = 0; j < 4; j++){ acc[i][j] = {0.f,0.f,0.f,0.f}; facc[i][j] = {0.f,0.f,0.f,0.f}; }

  auto stage = [&](int tt, int buf){
    const int ii = tt >> 2, k0 = (tt & 3) * 64;
    const u16* Ap = Ab + (size_t)ii * 65536;
    const u16* Wp = W1t + (size_t)ii * 131072;
#pragma unroll
    for(int i = 0; i < 2; i++){
      const int row = i * 64 + wv * 8 + lrow;
      gl_lds16(Ap + (size_t)(b0 + row) * 256 + k0 + csw * 8, &lA[buf][(i * 64 + wv * 8) * 64]);
    }
#pragma unroll
    for(int j = 0; j < 4; j++){
      const int n = j * 64 + wv * 8 + lrow;
      gl_lds16(Wp + (size_t)(o0 + n) * 256 + k0 + csw * 8, &lB[buf][(j * 64 + wv * 8) * 64]);
    }
  };

  stage(0, 0);
  stage(1, 1);

#pragma unroll
  for(int tt = 0; tt < 12; tt++){
    const int cur = tt & 1;
    if(tt < 11) asm volatile("s_waitcnt vmcnt(6)" ::: "memory");
    else        asm volatile("s_waitcnt vmcnt(0)" ::: "memory");
    __builtin_amdgcn_s_barrier();
#pragma unroll
    for(int ks = 0; ks < 2; ks++){
      bf16x8 af[4], bfr[4];
#pragma unroll
      for(int i = 0; i < 4; i++)
        af[i] = *reinterpret_cast<const bf16x8*>(
            &lA[cur][(wm * 64 + i * 16 + r) * 64 + (((ks * 4 + q) ^ rsw) * 8)]);
#pragma unroll
      for(int j = 0; j < 4; j++)
        bfr[j] = *reinterpret_cast<const bf16x8*>(
            &lB[cur][(wn * 64 + j * 16 + r) * 64 + (((ks * 4 + q) ^ rsw) * 8)]);
#pragma unroll
      for(int i = 0; i < 4; i++)
#pragma unroll
        for(int j = 0; j < 4; j++) acc[i][j] = MFMA(bfr[j], af[i], acc[i][j]);
    }
    if((tt & 3) == 3){   // i boundary: relu-flush into facc (registers only)
      const int ib = tt >> 2;
#pragma unroll
      for(int i = 0; i < 4; i++)
#pragma unroll
        for(int j = 0; j < 4; j++){
          const int col = o0 + wn * 64 + j * 16 + q * 4;
          const ushort4 b4 = *reinterpret_cast<const ushort4*>(b1 + ib * 512 + col);
          facc[i][j][0] += fmaxf(acc[i][j][0] + bf2f(b4.x), 0.f);
          facc[i][j][1] += fmaxf(acc[i][j][1] + bf2f(b4.y), 0.f);
          facc[i][j][2] += fmaxf(acc[i][j][2] + bf2f(b4.z), 0.f);
          facc[i][j][3] += fmaxf(acc[i][j][3] + bf2f(b4.w), 0.f);
          acc[i][j] = {0.f, 0.f, 0.f, 0.f};
        }
    }
    __builtin_amdgcn_s_barrier();
    if(tt + 2 < 12) stage(tt + 2, cur);
  }

  // swapped layout: row = b0 + wm*64 + i*16 + r, col = o0 + wn*64 + j*16 + q*4
#pragma unroll
  for(int i = 0; i < 4; i++){
    const int row = b0 + wm * 64 + i * 16 + r;
#pragma unroll
    for(int j = 0; j < 4; j++){
      const int col = o0 + wn * 64 + j * 16 + q * 4;
      *reinterpret_cast<f32x4*>(hbuf + (size_t)row * 512 + col) = facc[i][j];
    }
  }
}

// ---------------- out = h @ W2 + b2 (dtype-matched store)
__global__ __launch_bounds__(64) void readout2(const float* __restrict__ hbuf, const u16* __restrict__ W2,
                                               const u16* __restrict__ b2, void* __restrict__ out,
                                               const int* __restrict__ flag){
  int b = blockIdx.x, o = threadIdx.x;
  if(o >= 10) return;
  float a = bf2f(b2[o]);
  for(int k = 0; k < 512; k++) a += hbuf[(size_t)b * 512 + k] * bf2f(W2[k * 10 + o]);
  if(*flag) ((u16*)out)[b * 10 + o] = f2bf(a);
  else      ((float*)out)[b * 10 + o] = a;
}

extern "C" void kernel_launch(void* const* d_in, const int* in_sizes, int n_in,
                              void* d_out, int out_size, void* d_ws, size_t ws_size,
                              hipStream_t stream){
  const void* x_n = d_in[0];
  const void* x_e = d_in[1];
  const void* x_c = d_in[2];
  const int* n_up_b = (const int*)d_in[3];
  const int* n_up_i = (const int*)d_in[4];
  const int* n_up_j = (const int*)d_in[5];
  const int* n_up_e = (const int*)d_in[6];
  const int* e_up_b = (const int*)d_in[7];
  const int* e_up_i = (const int*)d_in[8];
  const int* e_up_j = (const int*)d_in[9];
  const int* e_up_c = (const int*)d_in[10];
  const int* eb_b = (const int*)d_in[11];
  const int* eb_i = (const int*)d_in[12];
  const int* eb_j = (const int*)d_in[13];
  const int* cb_b = (const int*)d_in[14];
  const int* cb_i = (const int*)d_in[15];
  const int* cb_j = (const int*)d_in[16];

  // ---- workspace carve-up (~174 MiB)
  char* base = (char*)d_ws; size_t off0 = 0;
  auto alloc = [&](size_t n)->char*{ char* p = base + off0; off0 = (off0 + n + 255) & ~(size_t)255; return p; };
  u16* xn = (u16*)alloc((size_t)MN * HD * 2);
  u16* xe = (u16*)alloc((size_t)ME * HD * 2);
  u16* xc = (u16*)alloc((size_t)MC * HD * 2);
  u16* BIG1 = (u16*)alloc((size_t)ME * HD * 2);      // Ze/BDe/Ye staging
  u16* SMa  = (u16*)alloc((size_t)MN * HD * 2);      // Yn then Zc; pool: REFn/Gn
  u16* SMb  = (u16*)alloc((size_t)MN * HD * 2);      // BDn; pool: REFc/Gc
  u16* ACC  = (u16*)alloc((size_t)ME * HD * 2);      // full-width bf16 gather acc; pool: REFe/Ge
  u16* wt = (u16*)alloc((size_t)38 * 65536 * 2);
  unsigned int* mask_e = (unsigned int*)alloc((size_t)NB * MAXE * MAXN / 8);  // dead after dedup -> params
  unsigned int* mask_c = (unsigned int*)alloc((size_t)NB * MAXC * MAXE / 8);
  unsigned char* valid_e = (unsigned char*)alloc(QE);
  unsigned char* valid_c = (unsigned char*)alloc(QC);
  float* pooled = (float*)alloc((size_t)3 * NB * HD * 4);   // also aliased as scan cursor
  float* hbuf   = (float*)alloc((size_t)NB * 512 * 4);
  int* flag     = (int*)alloc(256);
  int2* csrUp   = (int2*)alloc((size_t)UPTOT * 8);
  int* csrBd    = (int*)alloc((size_t)(QE + QC) * 4);
  int* hist     = (int*)alloc((size_t)HTOT * 4);
  int* offA     = (int*)alloc((size_t)HTOT * 4);
  int* bsum     = (int*)alloc(1024);
  u16* W1t      = (u16*)alloc((size_t)3 * 512 * 256 * 2);   // transposed W1 for readout1
  u16* pooledb  = (u16*)alloc((size_t)3 * NB * HD * 2);     // bf16 pooled for readout1_mfma
  int* cur      = (int*)pooled;   // scan cursor; pooled dead until pooling

  u16* wtSelf = wt;
  u16* wtUpx  = wt + (size_t)12 * 65536;
  u16* wtUpa  = wt + (size_t)20 * 65536;
  u16* wtB    = wt + (size_t)28 * 65536;
  u16* wtP    = wt + (size_t)36 * 65536;
  u16* wtPref = wt + (size_t)37 * 65536;

  // small converted params in mask_e's 1 MiB (dead after dedup)
  u16* W1c = (u16*)mask_e;
  u16* b1c = W1c + 393216;
  u16* W2c = b1c + 1536;
  u16* b2c = W2c + 5120;
  u16* bsc = b2c + 16;
  u16* bpc = bsc + 3072;

  // ---- prologue
  detect_dtype<<<1, 64, 0, stream>>>((const u16*)x_n, flag);
  // masks are contiguous allocations: one zero pass (1.5 MiB)
  zero_f4<<<(98304 + 255)/256, 256, 0, stream>>>((float*)mask_e, 98304);
  dedup_kernel<<<QE/256, 256, 0, stream>>>(eb_b, eb_i, eb_j, mask_e, valid_e, QE, MAXE, MAXN);
  dedup_kernel<<<QC/256, 256, 0, stream>>>(cb_b, cb_i, cb_j, mask_c, valid_c, QC, MAXC, MAXE);

  wt_all<<<dim3(16,16,38), dim3(16,16), 0, stream>>>(d_in[17], d_in[19], d_in[20],
                                                     d_in[21], d_in[22], d_in[23], wt, flag);
  conv3<<<14336, 256, 0, stream>>>(x_n, xn, x_e, xe, x_c, xc, flag);
  conv_params<<<197, 256, 0, stream>>>(d_in[25], W1c, d_in[26], b1c, d_in[27], W2c,
                                       d_in[28], b2c, d_in[18], bsc, d_in[24], bpc, flag);
  w1_transpose<<<dim3(32,16,3), dim3(16,16), 0, stream>>>(W1c, W1t);

  // ---- CSR build (histogram -> scan -> fill), fused
  zero_f4<<<(HTOT/4 + 255)/256, 256, 0, stream>>>((float*)hist, HTOT/4);
  hist_all<<<PN/256 + PE/256 + QE/256 + QC/256, 256, 0, stream>>>(
      n_up_b, n_up_i, e_up_b, e_up_i, eb_b, eb_i, valid_e, cb_b, cb_i, valid_c, hist);
  scan1<<<HTOT/1024, 256, 0, stream>>>(hist, bsum);
  scan2<<<1, 256, 0, stream>>>(bsum, HTOT/1024);
  scan3<<<HTOT/1024, 256, 0, stream>>>(hist, bsum, offA, cur);
  fill_all<<<PN/256 + PE/256 + QE/256 + QC/256, 256, 0, stream>>>(
      n_up_b, n_up_i, n_up_j, n_up_e, e_up_b, e_up_i, e_up_j, e_up_c,
      eb_b, eb_i, eb_j, valid_e, cb_b, cb_i, cb_j, valid_c, cur, csrUp, csrBd);

  // ---- layers (9 dispatches each)
  for(int l = 0; l < NLAYER; l++){
    const u16* Wupx0 = wtUpx + (size_t)(l*2+0) * 65536;
    const u16* Wupx1 = wtUpx + (size_t)(l*2+1) * 65536;
    const u16* Wupa0 = wtUpa + (size_t)(l*2+0) * 65536;
    const u16* Wupa1 = wtUpa + (size_t)(l*2+1) * 65536;
    const u16* Wb0   = wtB   + (size_t)(l*2+0) * 65536;
    const u16* Wb1   = wtB   + (size_t)(l*2+1) * 65536;
    const u16* Ws0   = wtSelf + (size_t)(l*3+0) * 65536;
    const u16* Ws1   = wtSelf + (size_t)(l*3+1) * 65536;
    const u16* Ws2   = wtSelf + (size_t)(l*3+2) * 65536;
    const u16* bs0 = bsc + (size_t)(l*3+0) * HD;
    const u16* bs1 = bsc + (size_t)(l*3+1) * HD;
    const u16* bs2 = bsc + (size_t)(l*3+2) * HD;

    // nodes: {Yn(SMa), Ze(BIG1), BDn(SMb)} from OLD xn/xe in ONE dispatch
    gemm_k<0><<<MN/64 + ME/64 + MN/64, 256, 0, stream>>>(
        xn, Wupx0, SMa, MN/64, xe, Wupa0, BIG1, ME/64, xn, Wb0, SMb,
        nullptr, nullptr, nullptr, nullptr);
    gather_k<1,0><<<MN/4, 256, 0, stream>>>(SMa, BIG1, nullptr, csrUp, csrBd,
                                            offA, hist, SEG_N, 0, ACC, 0);
    gemm_k<2><<<MN/64, 256, 0, stream>>>(xn, Ws0, xn, MN/64, xn, Ws0, xn, 0, xn, Ws0, xn,
                                         nullptr, nullptr, ACC, bs0);

    // cells: {Zc(SMa, held for edges), BDe(BIG1)} in ONE dispatch
    gemm_k<0><<<MC/64 + ME/64, 256, 0, stream>>>(
        xc, Wupa1, SMa, MC/64, xe, Wb1, BIG1, ME/64, xc, Wupa1, SMa,
        nullptr, nullptr, nullptr, nullptr);
    gather_k<0,1><<<MC/4, 256, 0, stream>>>(nullptr, nullptr, BIG1, csrUp, csrBd,
                                            offA, hist, 0, SEG_CB, ACC, 0);
    gemm_k<2><<<MC/64, 256, 0, stream>>>(xc, Ws2, xc, MC/64, xc, Ws2, xc, 0, xc, Ws2, xc,
                                         nullptr, nullptr, ACC, bs2);

    // edges: Ye(BIG1) from OLD xe; full-width gather + fused self
    gemm_k<0><<<ME/64, 256, 0, stream>>>(
        xe, Wupx1, BIG1, ME/64, xe, Wupx1, BIG1, 0, xe, Wupx1, BIG1,
        nullptr, nullptr, nullptr, nullptr);
    gather_k<1,1><<<ME/4, 256, 0, stream>>>(BIG1, SMa, SMb, csrUp, csrBd,
                                            offA, hist, SEG_E, SEG_EB, ACC, 0);
    gemm_k<2><<<ME/64, 256, 0, stream>>>(xe, Ws1, xe, ME/64, xe, Ws1, xe, 0, xe, Ws1, xe,
                                         nullptr, nullptr, ACC, bs1);
  }

  // ---- gated pooling: REFs into SMa/ACC/SMb, ONE segmented dual-A GEMM
  // (G aliases REF: per-block A2 rows fully staged before C rows written),
  // then one fused pool_all.
  conv3<<<14336, 256, 0, stream>>>(x_n, SMa, x_e, ACC, x_c, SMb, flag);
  {
    long np4 = (long)3 * NB * HD / 4;
    zero_f4<<<(int)((np4 + 255)/256), 256, 0, stream>>>(pooled, np4);
  }
  gemm_k<3><<<MN/64 + ME/64 + MC/64, 256, 0, stream>>>(
      xn, SMa, SMa, MN/64, xe, ACC, ACC, ME/64, xc, SMb, SMb,
      wtP, wtPref, nullptr, nullptr);
  pool_all<<<dim3(NB, 7), 256, 0, stream>>>(SMa, ACC, SMb, bpc, xn, xe, xc, pooled);

  // ---- readout
  conv_f2b<<<96, 256, 0, stream>>>(pooled, pooledb, (long)3 * NB * HD);
  readout1_mfma<<<dim3(2,2), 512, 0, stream>>>(pooledb, W1t, b1c, hbuf);
  readout2<<<NB, 64, 0, stream>>>(hbuf, W2c, b2c, d_out, flag);
}

// Round 9
// 1255.461 us; speedup vs baseline: 1.0678x; 1.0551x over previous
//
#include <hip/hip_runtime.h>
#include <cstdint>
#include <cstddef>

typedef unsigned short u16;
typedef __bf16 bf16x8 __attribute__((ext_vector_type(8)));
typedef float f32x4 __attribute__((ext_vector_type(4)));
typedef unsigned short u16x8 __attribute__((ext_vector_type(8)));

#define NB   256
#define MAXN 128
#define MAXE 256
#define MAXC 64
#define HD   256
#define NLAYER 4
#define PN 131072
#define PE 98304
#define QE 131072
#define QC 65536
#define MN (NB*MAXN)   /* 32768 node rows  */
#define ME (NB*MAXE)   /* 65536 edge rows  */
#define MC (NB*MAXC)   /* 16384 cell rows  */

// CSR segment bases in the concatenated histogram/offset arrays
#define SEG_N  0
#define SEG_E  (MN)
#define SEG_EB (MN + ME)
#define SEG_CB (MN + 2*ME)
#define HTOT   (MN + 2*ME + MC)      /* 229376, divisible by 1024 */
#define UPTOT  (PN + PE)             /* csrBd global-index base   */

__device__ __forceinline__ float bf2f(u16 u){
  union{unsigned int i; float f;} x; x.i = ((unsigned int)u) << 16; return x.f;
}
__device__ __forceinline__ u16 f2bf(float f){
  union{float f; unsigned int i;} x; x.f = f;
  unsigned int r = x.i + 0x7fffu + ((x.i >> 16) & 1u);
  return (u16)(r >> 16);
}
__device__ __forceinline__ f32x4 MFMA(bf16x8 a, bf16x8 b, f32x4 c){
  return __builtin_amdgcn_mfma_f32_16x16x32_bf16(a, b, c, 0, 0, 0);
}
// async global->LDS, 16B per lane; lds base wave-uniform (lane*16 implicit)
__device__ __forceinline__ void gl_lds16(const u16* g, u16* l){
  __builtin_amdgcn_global_load_lds(
      (const __attribute__((address_space(1))) unsigned int*)g,
      (__attribute__((address_space(3))) unsigned int*)l, 16, 0, 0);
}

// ---------------- dtype sniff (bf16 vs f32 input buffers)
__global__ void detect_dtype(const u16* __restrict__ x, int* __restrict__ flag){
  if(threadIdx.x == 0 && blockIdx.x == 0){
    int cnt = 0;
    for(int i = 0; i < 64; i++){
      int e = (x[i] >> 7) & 0xFF;
      if(e >= 118 && e <= 136) cnt++;
    }
    *flag = (cnt >= 50) ? 1 : 0;   // 1 = bf16, 0 = f32
  }
}

// ---------------- conv helper: one 8-elem unit at offset i of span (s,d,n)
__device__ __forceinline__ void convSpan(const void* s, u16* d, long n, long i, int isbf){
  if(i + 8 <= n){
    if(isbf){
      *reinterpret_cast<u16x8*>(d + i) = *reinterpret_cast<const u16x8*>((const u16*)s + i);
    }else{
      const float* sp = (const float*)s + i;
      float4 a = *reinterpret_cast<const float4*>(sp);
      float4 b = *reinterpret_cast<const float4*>(sp + 4);
      u16x8 o;
      o[0]=f2bf(a.x); o[1]=f2bf(a.y); o[2]=f2bf(a.z); o[3]=f2bf(a.w);
      o[4]=f2bf(b.x); o[5]=f2bf(b.y); o[6]=f2bf(b.z); o[7]=f2bf(b.w);
      *reinterpret_cast<u16x8*>(d + i) = o;
    }
  }else{
    for(long e = i; e < n; e++)
      d[e] = isbf ? ((const u16*)s)[e] : f2bf(((const float*)s)[e]);
  }
}

// ---------------- fused 3-target feature conversion (n/e/c shapes fixed)
__global__ __launch_bounds__(256) void conv3(const void* __restrict__ s0, u16* __restrict__ d0,
                                             const void* __restrict__ s1, u16* __restrict__ d1,
                                             const void* __restrict__ s2, u16* __restrict__ d2,
                                             const int* __restrict__ flag){
  const long U0 = (long)MN * HD / 8, U1 = (long)ME * HD / 8, U2 = (long)MC * HD / 8;
  long u = (long)blockIdx.x * 256 + threadIdx.x;
  const int isbf = *flag;
  if(u < U0){ convSpan(s0, d0, (long)MN * HD, u * 8, isbf); return; }
  u -= U0;
  if(u < U1){ convSpan(s1, d1, (long)ME * HD, u * 8, isbf); return; }
  u -= U1;
  if(u < U2) convSpan(s2, d2, (long)MC * HD, u * 8, isbf);
}

// ---------------- fused small-parameter conversion (6 spans)
__global__ __launch_bounds__(256) void conv_params(
    const void* sW1, u16* dW1, const void* sb1, u16* db1,
    const void* sW2, u16* dW2, const void* sb2, u16* db2,
    const void* sbs, u16* dbs, const void* sbp, u16* dbp,
    const int* __restrict__ flag){
  long u = (long)blockIdx.x * 256 + threadIdx.x;
  const int isbf = *flag;
  if(u < 49152){ convSpan(sW1, dW1, 393216, u * 8, isbf); return; } u -= 49152;
  if(u < 192)  { convSpan(sb1, db1, 1536,   u * 8, isbf); return; } u -= 192;
  if(u < 640)  { convSpan(sW2, dW2, 5120,   u * 8, isbf); return; } u -= 640;
  if(u < 2)    { convSpan(sb2, db2, 10,     u * 8, isbf); return; } u -= 2;
  if(u < 384)  { convSpan(sbs, dbs, 3072,   u * 8, isbf); return; } u -= 384;
  if(u < 32)     convSpan(sbp, dbp, 256,    u * 8, isbf);
}

// ---------------- f32 -> bf16 (always f32 source; for pooled)
__global__ __launch_bounds__(256) void conv_f2b(const float* __restrict__ s, u16* __restrict__ d, long n){
  long i = ((long)blockIdx.x * 256 + threadIdx.x) * 8;
  if(i >= n) return;
  float4 a = *reinterpret_cast<const float4*>(s + i);
  float4 b = *reinterpret_cast<const float4*>(s + i + 4);
  u16x8 o;
  o[0]=f2bf(a.x); o[1]=f2bf(a.y); o[2]=f2bf(a.z); o[3]=f2bf(a.w);
  o[4]=f2bf(b.x); o[5]=f2bf(b.y); o[6]=f2bf(b.z); o[7]=f2bf(b.w);
  *reinterpret_cast<u16x8*>(d + i) = o;
}

// ---------------- zero fill
__global__ __launch_bounds__(256) void zero_f4(float* __restrict__ p, long n4){
  long i = (long)blockIdx.x * blockDim.x + threadIdx.x;
  if(i >= n4) return;
  float4 z = {0.f, 0.f, 0.f, 0.f};
  *reinterpret_cast<float4*>(p + i * 4) = z;
}

// ---------------- fused weight transpose: 38 [256,256] slices -> bf16 [n*256+k]
// z<12: Wself, z<20: Wupx, z<28: Wupa, z<36: Wb, z==36: Wp, z==37: Wp_ref
__global__ void wt_all(const void* __restrict__ pSelf, const void* __restrict__ pUpx,
                       const void* __restrict__ pUpa, const void* __restrict__ pB,
                       const void* __restrict__ pP, const void* __restrict__ pPref,
                       u16* __restrict__ wt, const int* __restrict__ flag){
  __shared__ u16 t[16][17];
  int z = blockIdx.z;
  const void* src; int m; u16* dst;
  if(z < 12)      { src = pSelf; m = z;      dst = wt; }
  else if(z < 20) { src = pUpx;  m = z - 12; dst = wt + (size_t)12 * 65536; }
  else if(z < 28) { src = pUpa;  m = z - 20; dst = wt + (size_t)20 * 65536; }
  else if(z < 36) { src = pB;    m = z - 28; dst = wt + (size_t)28 * 65536; }
  else if(z == 36){ src = pP;    m = 0;      dst = wt + (size_t)36 * 65536; }
  else            { src = pPref; m = 0;      dst = wt + (size_t)37 * 65536; }
  int n0 = blockIdx.x * 16, k0 = blockIdx.y * 16;
  size_t sidx = (size_t)m * 65536 + (size_t)(k0 + threadIdx.y) * 256 + n0 + threadIdx.x;
  u16 v = (*flag) ? ((const u16*)src)[sidx] : f2bf(((const float*)src)[sidx]);
  t[threadIdx.y][threadIdx.x] = v;
  __syncthreads();
  dst[(size_t)m * 65536 + (size_t)(n0 + threadIdx.y) * 256 + (k0 + threadIdx.x)] =
      t[threadIdx.x][threadIdx.y];
}

// ---------------- W1 transpose: src bf16 [3][256 k][512 o] -> dst [3][512 o][256 k]
__global__ void w1_transpose(const u16* __restrict__ src, u16* __restrict__ dst){
  __shared__ u16 t[16][17];
  int i = blockIdx.z;
  int o0 = blockIdx.x * 16, k0 = blockIdx.y * 16;
  t[threadIdx.y][threadIdx.x] =
      src[(size_t)i * 131072 + (size_t)(k0 + threadIdx.y) * 512 + o0 + threadIdx.x];
  __syncthreads();
  dst[(size_t)i * 131072 + (size_t)(o0 + threadIdx.y) * 256 + (k0 + threadIdx.x)] =
      t[threadIdx.x][threadIdx.y];
}

// ---------------- dedup boundary incidences (.set(1.0): idempotent)
__global__ void dedup_kernel(const int* __restrict__ bb, const int* __restrict__ bi,
                             const int* __restrict__ bj, unsigned int* __restrict__ mask,
                             unsigned char* __restrict__ valid, int Q, int maxI, int maxJ){
  int q = blockIdx.x * blockDim.x + threadIdx.x;
  if(q >= Q) return;
  int s = (bb[q] * maxI + bi[q]) * maxJ + bj[q];
  unsigned int bit = 1u << (s & 31);
  unsigned int old = atomicOr(&mask[s >> 5], bit);
  valid[q] = (old & bit) ? 0 : 1;
}

// ---------------- fused CSR histogram over all 4 segments
__global__ __launch_bounds__(256) void hist_all(
    const int* __restrict__ nub, const int* __restrict__ nui,
    const int* __restrict__ eub, const int* __restrict__ eui,
    const int* __restrict__ ebb, const int* __restrict__ ebi, const unsigned char* __restrict__ ve,
    const int* __restrict__ cbb, const int* __restrict__ cbi, const unsigned char* __restrict__ vc,
    int* __restrict__ hist){
  int bx = blockIdx.x, t = threadIdx.x;
  if(bx < PN/256){
    int p = bx * 256 + t;
    atomicAdd(&hist[SEG_N + nub[p] * MAXN + nui[p]], 1);
  }else if(bx < PN/256 + PE/256){
    int p = (bx - PN/256) * 256 + t;
    atomicAdd(&hist[SEG_E + eub[p] * MAXE + eui[p]], 1);
  }else if(bx < PN/256 + PE/256 + QE/256){
    int q = (bx - PN/256 - PE/256) * 256 + t;
    if(ve[q]) atomicAdd(&hist[SEG_EB + ebb[q] * MAXE + ebi[q]], 1);
  }else{
    int q = (bx - PN/256 - PE/256 - QE/256) * 256 + t;
    if(vc[q]) atomicAdd(&hist[SEG_CB + cbb[q] * MAXC + cbi[q]], 1);
  }
}

// ---------------- 3-phase exclusive scan over HTOT ints (1024 elems / block)
__global__ __launch_bounds__(256) void scan1(const int* __restrict__ hist, int* __restrict__ bsum){
  __shared__ int s[256];
  int t = threadIdx.x;
  long base = (long)blockIdx.x * 1024 + t * 4;
  int4 v = *reinterpret_cast<const int4*>(hist + base);
  s[t] = v.x + v.y + v.z + v.w;
  __syncthreads();
  for(int st = 128; st > 0; st >>= 1){
    if(t < st) s[t] += s[t + st];
    __syncthreads();
  }
  if(t == 0) bsum[blockIdx.x] = s[0];
}
__global__ __launch_bounds__(256) void scan2(int* __restrict__ bsum, int nb){
  __shared__ int s[256];
  int t = threadIdx.x;
  int v = (t < nb) ? bsum[t] : 0;
  s[t] = v;
  __syncthreads();
  for(int st = 1; st < 256; st <<= 1){
    int u = (t >= st) ? s[t - st] : 0;
    __syncthreads();
    s[t] += u;
    __syncthreads();
  }
  if(t < nb) bsum[t] = s[t] - v;   // exclusive
}
__global__ __launch_bounds__(256) void scan3(const int* __restrict__ hist, const int* __restrict__ bsum,
                                             int* __restrict__ off, int* __restrict__ cur){
  __shared__ int s[256];
  int t = threadIdx.x;
  long base = (long)blockIdx.x * 1024 + t * 4;
  int4 v = *reinterpret_cast<const int4*>(hist + base);
  int sum = v.x + v.y + v.z + v.w;
  s[t] = sum;
  __syncthreads();
  for(int st = 1; st < 256; st <<= 1){
    int u = (t >= st) ? s[t - st] : 0;
    __syncthreads();
    s[t] += u;
    __syncthreads();
  }
  int excl = s[t] - sum + bsum[blockIdx.x];
  int4 o;
  o.x = excl; o.y = o.x + v.x; o.z = o.y + v.y; o.w = o.z + v.z;
  *reinterpret_cast<int4*>(off + base) = o;
  *reinterpret_cast<int4*>(cur + base) = o;
}

// ---------------- fused CSR fill over all 4 segments
__global__ __launch_bounds__(256) void fill_all(
    const int* __restrict__ nub, const int* __restrict__ nui,
    const int* __restrict__ nuj, const int* __restrict__ nue,
    const int* __restrict__ eub, const int* __restrict__ eui,
    const int* __restrict__ euj, const int* __restrict__ euc,
    const int* __restrict__ ebb, const int* __restrict__ ebi,
    const int* __restrict__ ebj, const unsigned char* __restrict__ ve,
    const int* __restrict__ cbb, const int* __restrict__ cbi,
    const int* __restrict__ cbj, const unsigned char* __restrict__ vc,
    int* __restrict__ cur, int2* __restrict__ csrUp, int* __restrict__ csrBd){
  int bx = blockIdx.x, t = threadIdx.x;
  if(bx < PN/256){
    int p = bx * 256 + t; int b = nub[p];
    int pos = atomicAdd(&cur[SEG_N + b * MAXN + nui[p]], 1);
    int2 e; e.x = b * MAXN + nuj[p]; e.y = b * MAXE + nue[p];
    csrUp[pos] = e;
  }else if(bx < PN/256 + PE/256){
    int p = (bx - PN/256) * 256 + t; int b = eub[p];
    int pos = atomicAdd(&cur[SEG_E + b * MAXE + eui[p]], 1);
    int2 e; e.x = b * MAXE + euj[p]; e.y = b * MAXC + euc[p];
    csrUp[pos] = e;
  }else if(bx < PN/256 + PE/256 + QE/256){
    int q = (bx - PN/256 - PE/256) * 256 + t;
    if(!ve[q]) return;
    int b = ebb[q];
    int pos = atomicAdd(&cur[SEG_EB + b * MAXE + ebi[q]], 1);
    csrBd[pos - UPTOT] = b * MAXN + ebj[q];
  }else{
    int q = (bx - PN/256 - PE/256 - QE/256) * 256 + t;
    if(!vc[q]) return;
    int b = cbb[q];
    int pos = atomicAdd(&cur[SEG_CB + b * MAXC + cbi[q]], 1);
    csrBd[pos - UPTOT] = b * MAXE + cbj[q];
  }
}

// ---------------- gather: one wave per receiver row; bf16 ACC store; XCD swizzle.
// v2: depth-2 neighbor prefetch (issue k+1's csr entry + feature rows before
// consuming k's) to hide the dependent-load chain latency per neighbor.
template<int HAS_UP, int HAS_BD>
__global__ __launch_bounds__(256) void gather_k(
    const u16* __restrict__ Y, const u16* __restrict__ Z, const u16* __restrict__ BD,
    const int2* __restrict__ csrUp, const int* __restrict__ csrBd,
    const int* __restrict__ off, const int* __restrict__ deg,
    int upBase, int bdBase, u16* __restrict__ ACC, int rowLo){
  const int nb = gridDim.x;
  int bx = blockIdx.x;
  if((nb & 7) == 0) bx = (bx & 7) * (nb >> 3) + (bx >> 3);   // XCD-contiguous ranges
  const int row = rowLo + bx * 4 + (threadIdx.x >> 6);
  const int lane = threadIdx.x & 63;
  const int c = lane * 4;
  float a0 = 0.f, a1 = 0.f, a2 = 0.f, a3 = 0.f;
  if(HAS_UP){
    int s = off[upBase + row];
    int d = deg[upBase + row];
    if(d > 0){
      int2 e = csrUp[s];
      ushort4 y0 = *reinterpret_cast<const ushort4*>(Y + (size_t)e.x * 256 + c);
      ushort4 z0 = *reinterpret_cast<const ushort4*>(Z + (size_t)e.y * 256 + c);
      for(int k = 1; k <= d; k++){
        ushort4 y1 = y0, z1 = z0;
        if(k < d){
          int2 e2 = csrUp[s + k];
          y1 = *reinterpret_cast<const ushort4*>(Y + (size_t)e2.x * 256 + c);
          z1 = *reinterpret_cast<const ushort4*>(Z + (size_t)e2.y * 256 + c);
        }
        a0 += fmaxf(bf2f(y0.x) + bf2f(z0.x), 0.f);
        a1 += fmaxf(bf2f(y0.y) + bf2f(z0.y), 0.f);
        a2 += fmaxf(bf2f(y0.z) + bf2f(z0.z), 0.f);
        a3 += fmaxf(bf2f(y0.w) + bf2f(z0.w), 0.f);
        y0 = y1; z0 = z1;
      }
    }
  }
  if(HAS_BD){
    int s = off[bdBase + row] - UPTOT;
    int d = deg[bdBase + row];
    if(d > 0){
      int j = csrBd[s];
      ushort4 x0 = *reinterpret_cast<const ushort4*>(BD + (size_t)j * 256 + c);
      for(int k = 1; k <= d; k++){
        ushort4 x1 = x0;
        if(k < d){
          int j2 = csrBd[s + k];
          x1 = *reinterpret_cast<const ushort4*>(BD + (size_t)j2 * 256 + c);
        }
        a0 += bf2f(x0.x); a1 += bf2f(x0.y); a2 += bf2f(x0.z); a3 += bf2f(x0.w);
        x0 = x1;
      }
    }
  }
  ushort4 o; o.x = f2bf(a0); o.y = f2bf(a1); o.z = f2bf(a2); o.w = f2bf(a3);
  *reinterpret_cast<ushort4*>(ACC + (size_t)(row - rowLo) * 256 + c) = o;
}

// ---------------- LDS-staged bf16 MFMA GEMM, v7: round-5 BK=64 core
// (62.4us measured, 0 conflicts) with 8 waves of 64x32 instead of 4 waves
// of 64x64. Identical LDS (80 KiB -> 2 blocks/CU), identical barrier count,
// identical per-SIMD MFMA volume, identical r&7 swizzle -- but 16 waves/CU
// (4/SIMD) instead of 8 (2/SIMD): direct TLP remedy for round-5's
// correlated-barrier-stall latency binding. (BK=32 branch refuted in r8:
// conflicts 0 but 67.6us > 62.4 -- barrier density, not conflicts.)
// Counted-vmcnt depth-2: 5 loads/wave/tile (1 lA + 4 lB), steady vmcnt(5),
// drain only at last tile. Pre-swizzled global source + linear
// global_load_lds dest + swizzled read (both-sides rule).
// Operand-swapped MFMA -> ushort4 8B epilogue stores. 3-way segmented grid.
// MODE 0: C = P@Q.
// MODE 2: C = relu(P@Q + ACCbf + bias), C may alias P.   (single segment)
// MODE 3: C = P@S1 + Q@S2  (P=x, Q=ref, shared weights). C may alias Q.
template<int MODE>
__global__ __launch_bounds__(512) void gemm_k(
    const u16* P0, const u16* Q0, u16* C0, int n0,
    const u16* P1, const u16* Q1, u16* C1, int n1,
    const u16* P2, const u16* Q2, u16* C2,
    const u16* __restrict__ S1, const u16* __restrict__ S2,
    const u16* __restrict__ ACC, const u16* __restrict__ bias){
  __shared__ u16 lA[2][64 * 64];    // [buf][row][k-chunk swizzled]   8 KiB/buf
  __shared__ u16 lB[2][256 * 64];   // [buf][n][k-chunk swizzled]    32 KiB/buf
  int bx = blockIdx.x;
  const u16* P = P0; const u16* Q = Q0; u16* C = C0;
  if(bx >= n0 + n1){ bx -= n0 + n1; P = P2; Q = Q2; C = C2; }
  else if(bx >= n0){ bx -= n0;      P = P1; Q = Q1; C = C1; }
  const int t = threadIdx.x;
  const int lane = t & 63, wv = t >> 6;   // 8 waves; each: 64 rows x 32 cols
  const int r = lane & 15, q = lane >> 4;
  const int rsw = r & 7;                   // read-side XOR key (row&7), r5-proven
  const size_t m0 = (size_t)bx * 64;
  const int lrow = lane >> 3, lchk = lane & 7;
  const int csw = lchk ^ lrow;             // source chunk pre-swizzle (lrow==row&7)

  f32x4 acc[4][2];
#pragma unroll
  for(int i = 0; i < 4; i++)
#pragma unroll
    for(int j = 0; j < 2; j++) acc[i][j] = {0.f, 0.f, 0.f, 0.f};

  const int NT = (MODE == 3) ? 8 : 4;      // tiles: (src, k0) flattened

  auto stage = [&](int tt, int buf){
    const u16* Ap = (MODE == 3) ? ((tt >= 4) ? Q : P) : P;
    const u16* Wp = (MODE == 3) ? ((tt >= 4) ? S2 : S1) : Q;
    const int k0 = (tt & 3) * 64;
    // lA: 64 rows; wave wv stages rows [wv*8, wv*8+8) in ONE load
    gl_lds16(Ap + (m0 + wv * 8 + lrow) * 256 + k0 + csw * 8,
             &lA[buf][(wv * 8) * 64]);
    // lB: 256 rows; wave stages rows [wv*32, wv*32+32) = 4 loads
#pragma unroll
    for(int j = 0; j < 4; j++){
      const int n = wv * 32 + j * 8 + lrow;
      gl_lds16(Wp + (size_t)n * 256 + k0 + csw * 8,
               &lB[buf][(wv * 32 + j * 8) * 64]);
    }
  };

  // prologue: depth-2 prefetch (10 loads/wave in flight)
  stage(0, 0);
  stage(1, 1);

#pragma unroll
  for(int tt = 0; tt < NT; tt++){
    const int cur = tt & 1;
    // tile tt landed; tile tt+1 (if any) stays in flight across the barrier
    if(tt < NT - 1) asm volatile("s_waitcnt vmcnt(5)" ::: "memory");
    else            asm volatile("s_waitcnt vmcnt(0)" ::: "memory");
    __builtin_amdgcn_s_barrier();
    __builtin_amdgcn_s_setprio(1);
#pragma unroll
    for(int ks = 0; ks < 2; ks++){
      bf16x8 af[4], bfr[2];
#pragma unroll
      for(int i = 0; i < 4; i++)
        af[i] = *reinterpret_cast<const bf16x8*>(
            &lA[cur][(i * 16 + r) * 64 + (((ks * 4 + q) ^ rsw) * 8)]);
#pragma unroll
      for(int j = 0; j < 2; j++)
        bfr[j] = *reinterpret_cast<const bf16x8*>(
            &lB[cur][(wv * 32 + j * 16 + r) * 64 + (((ks * 4 + q) ^ rsw) * 8)]);
      // operand-swapped: D[row<-n][col<-m]; per thread n = q*4+reg, m = r
#pragma unroll
      for(int i = 0; i < 4; i++)
#pragma unroll
        for(int j = 0; j < 2; j++) acc[i][j] = MFMA(bfr[j], af[i], acc[i][j]);
    }
    __builtin_amdgcn_s_setprio(0);
    __builtin_amdgcn_s_barrier();   // all waves done reading buf cur
    if(tt + 2 < NT) stage(tt + 2, cur);   // refill the consumed buffer
  }

  // epilogue (swapped layout): row = m0 + i*16 + r, col = wv*32 + j*16 + q*4 + reg
#pragma unroll
  for(int i = 0; i < 4; i++){
    const size_t row = m0 + i * 16 + r;
#pragma unroll
    for(int j = 0; j < 2; j++){
      const int col = wv * 32 + j * 16 + q * 4;
      const size_t idx = row * 256 + col;
      f32x4 v = acc[i][j];
      ushort4 o;
      if(MODE == 2){
        const ushort4 a4 = *reinterpret_cast<const ushort4*>(ACC + idx);
        const ushort4 b4 = *reinterpret_cast<const ushort4*>(bias + col);
        o.x = f2bf(fmaxf(v[0] + bf2f(a4.x) + bf2f(b4.x), 0.f));
        o.y = f2bf(fmaxf(v[1] + bf2f(a4.y) + bf2f(b4.y), 0.f));
        o.z = f2bf(fmaxf(v[2] + bf2f(a4.z) + bf2f(b4.z), 0.f));
        o.w = f2bf(fmaxf(v[3] + bf2f(a4.w) + bf2f(b4.w), 0.f));
      }else{
        o.x = f2bf(v[0]); o.y = f2bf(v[1]); o.z = f2bf(v[2]); o.w = f2bf(v[3]);
      }
      *reinterpret_cast<ushort4*>(C + idx) = o;
    }
  }
}

// ---------------- fused gated pooling reduce over all 3 dims
// grid (NB, 7): y<2 -> nodes (2 chunks), y<6 -> edges (4 chunks), y==6 -> cells.
__global__ __launch_bounds__(256) void pool_all(
    const u16* __restrict__ Gn, const u16* __restrict__ Ge, const u16* __restrict__ Gc,
    const u16* __restrict__ bpv,
    const u16* __restrict__ Xn, const u16* __restrict__ Xe, const u16* __restrict__ Xc,
    float* __restrict__ pooled){
  int b = blockIdx.x, h = threadIdx.x, y = blockIdx.y;
  const u16 *G, *X; float* out; int maxR, r0;
  if(y < 2)      { G = Gn; X = Xn; out = pooled;                    maxR = MAXN; r0 = y * 64; }
  else if(y < 6) { G = Ge; X = Xe; out = pooled + (size_t)NB * HD;  maxR = MAXE; r0 = (y - 2) * 64; }
  else           { G = Gc; X = Xc; out = pooled + (size_t)2*NB*HD;  maxR = MAXC; r0 = 0; }
  float bias = bf2f(bpv[h]);
  float acc = 0.f;
  for(int r = r0; r < r0 + 64; r++){
    size_t o = ((size_t)b * maxR + r) * 256 + h;
    float t = bf2f(G[o]) + bias;
    float w = 1.f / (1.f + __expf(-t));
    acc += w * bf2f(X[o]);
  }
  atomicAdd(&out[b * 256 + h], acc);
}

// ---------------- readout1 as MFMA GEMM (swapped-operand layout)
__global__ __launch_bounds__(512) void readout1_mfma(const u16* __restrict__ Ab,
                                                     const u16* __restrict__ W1t,
                                                     const u16* __restrict__ b1,
                                                     float* __restrict__ hbuf){
  __shared__ u16 lA[2][128 * 64];
  __shared__ u16 lB[2][256 * 64];
  const int t = threadIdx.x;
  const int lane = t & 63, wv = t >> 6;
  const int wm = wv >> 2, wn = wv & 3;      // 2 x 4 wave grid, each 64x64
  const int r = lane & 15, q = lane >> 4;
  const int rsw = r & 7;
  const int b0 = blockIdx.x * 128;
  const int o0 = blockIdx.y * 256;
  const int lrow = lane >> 3, lchk = lane & 7;
  const int csw = lchk ^ lrow;

  f32x4 acc[4][4], facc[4][4];
#pragma unroll
  for(int i = 0; i < 4; i++)
#pragma unroll
    for(int j = 0; j < 4; j++){ acc[i][j] = {0.f,0.f,0.f,0.f}; facc[i][j] = {0.f,0.f,0.f,0.f}; }

  auto stage = [&](int tt, int buf){
    const int ii = tt >> 2, k0 = (tt & 3) * 64;
    const u16* Ap = Ab + (size_t)ii * 65536;
    const u16* Wp = W1t + (size_t)ii * 131072;
#pragma unroll
    for(int i = 0; i < 2; i++){
      const int row = i * 64 + wv * 8 + lrow;
      gl_lds16(Ap + (size_t)(b0 + row) * 256 + k0 + csw * 8, &lA[buf][(i * 64 + wv * 8) * 64]);
    }
#pragma unroll
    for(int j = 0; j < 4; j++){
      const int n = j * 64 + wv * 8 + lrow;
      gl_lds16(Wp + (size_t)(o0 + n) * 256 + k0 + csw * 8, &lB[buf][(j * 64 + wv * 8) * 64]);
    }
  };

  stage(0, 0);
  stage(1, 1);

#pragma unroll
  for(int tt = 0; tt < 12; tt++){
    const int cur = tt & 1;
    if(tt < 11) asm volatile("s_waitcnt vmcnt(6)" ::: "memory");
    else        asm volatile("s_waitcnt vmcnt(0)" ::: "memory");
    __builtin_amdgcn_s_barrier();
#pragma unroll
    for(int ks = 0; ks < 2; ks++){
      bf16x8 af[4], bfr[4];
#pragma unroll
      for(int i = 0; i < 4; i++)
        af[i] = *reinterpret_cast<const bf16x8*>(
            &lA[cur][(wm * 64 + i * 16 + r) * 64 + (((ks * 4 + q) ^ rsw) * 8)]);
#pragma unroll
      for(int j = 0; j < 4; j++)
        bfr[j] = *reinterpret_cast<const bf16x8*>(
            &lB[cur][(wn * 64 + j * 16 + r) * 64 + (((ks * 4 + q) ^ rsw) * 8)]);
#pragma unroll
      for(int i = 0; i < 4; i++)
#pragma unroll
        for(int j = 0; j < 4; j++) acc[i][j] = MFMA(bfr[j], af[i], acc[i][j]);
    }
    if((tt & 3) == 3){   // i boundary: relu-flush into facc (registers only)
      const int ib = tt >> 2;
#pragma unroll
      for(int i = 0; i < 4; i++)
#pragma unroll
        for(int j = 0; j < 4; j++){
          const int col = o0 + wn * 64 + j * 16 + q * 4;
          const ushort4 b4 = *reinterpret_cast<const ushort4*>(b1 + ib * 512 + col);
          facc[i][j][0] += fmaxf(acc[i][j][0] + bf2f(b4.x), 0.f);
          facc[i][j][1] += fmaxf(acc[i][j][1] + bf2f(b4.y), 0.f);
          facc[i][j][2] += fmaxf(acc[i][j][2] + bf2f(b4.z), 0.f);
          facc[i][j][3] += fmaxf(acc[i][j][3] + bf2f(b4.w), 0.f);
          acc[i][j] = {0.f, 0.f, 0.f, 0.f};
        }
    }
    __builtin_amdgcn_s_barrier();
    if(tt + 2 < 12) stage(tt + 2, cur);
  }

  // swapped layout: row = b0 + wm*64 + i*16 + r, col = o0 + wn*64 + j*16 + q*4
#pragma unroll
  for(int i = 0; i < 4; i++){
    const int row = b0 + wm * 64 + i * 16 + r;
#pragma unroll
    for(int j = 0; j < 4; j++){
      const int col = o0 + wn * 64 + j * 16 + q * 4;
      *reinterpret_cast<f32x4*>(hbuf + (size_t)row * 512 + col) = facc[i][j];
    }
  }
}

// ---------------- out = h @ W2 + b2 (dtype-matched store)
__global__ __launch_bounds__(64) void readout2(const float* __restrict__ hbuf, const u16* __restrict__ W2,
                                               const u16* __restrict__ b2, void* __restrict__ out,
                                               const int* __restrict__ flag){
  int b = blockIdx.x, o = threadIdx.x;
  if(o >= 10) return;
  float a = bf2f(b2[o]);
  for(int k = 0; k < 512; k++) a += hbuf[(size_t)b * 512 + k] * bf2f(W2[k * 10 + o]);
  if(*flag) ((u16*)out)[b * 10 + o] = f2bf(a);
  else      ((float*)out)[b * 10 + o] = a;
}

extern "C" void kernel_launch(void* const* d_in, const int* in_sizes, int n_in,
                              void* d_out, int out_size, void* d_ws, size_t ws_size,
                              hipStream_t stream){
  const void* x_n = d_in[0];
  const void* x_e = d_in[1];
  const void* x_c = d_in[2];
  const int* n_up_b = (const int*)d_in[3];
  const int* n_up_i = (const int*)d_in[4];
  const int* n_up_j = (const int*)d_in[5];
  const int* n_up_e = (const int*)d_in[6];
  const int* e_up_b = (const int*)d_in[7];
  const int* e_up_i = (const int*)d_in[8];
  const int* e_up_j = (const int*)d_in[9];
  const int* e_up_c = (const int*)d_in[10];
  const int* eb_b = (const int*)d_in[11];
  const int* eb_i = (const int*)d_in[12];
  const int* eb_j = (const int*)d_in[13];
  const int* cb_b = (const int*)d_in[14];
  const int* cb_i = (const int*)d_in[15];
  const int* cb_j = (const int*)d_in[16];

  // ---- workspace carve-up (~174 MiB)
  char* base = (char*)d_ws; size_t off0 = 0;
  auto alloc = [&](size_t n)->char*{ char* p = base + off0; off0 = (off0 + n + 255) & ~(size_t)255; return p; };
  u16* xn = (u16*)alloc((size_t)MN * HD * 2);
  u16* xe = (u16*)alloc((size_t)ME * HD * 2);
  u16* xc = (u16*)alloc((size_t)MC * HD * 2);
  u16* BIG1 = (u16*)alloc((size_t)ME * HD * 2);      // Ze/BDe/Ye staging
  u16* SMa  = (u16*)alloc((size_t)MN * HD * 2);      // Yn then Zc; pool: REFn/Gn
  u16* SMb  = (u16*)alloc((size_t)MN * HD * 2);      // BDn; pool: REFc/Gc
  u16* ACC  = (u16*)alloc((size_t)ME * HD * 2);      // full-width bf16 gather acc; pool: REFe/Ge
  u16* wt = (u16*)alloc((size_t)38 * 65536 * 2);
  unsigned int* mask_e = (unsigned int*)alloc((size_t)NB * MAXE * MAXN / 8);  // dead after dedup -> params
  unsigned int* mask_c = (unsigned int*)alloc((size_t)NB * MAXC * MAXE / 8);
  unsigned char* valid_e = (unsigned char*)alloc(QE);
  unsigned char* valid_c = (unsigned char*)alloc(QC);
  float* pooled = (float*)alloc((size_t)3 * NB * HD * 4);   // also aliased as scan cursor
  float* hbuf   = (float*)alloc((size_t)NB * 512 * 4);
  int* flag     = (int*)alloc(256);
  int2* csrUp   = (int2*)alloc((size_t)UPTOT * 8);
  int* csrBd    = (int*)alloc((size_t)(QE + QC) * 4);
  int* hist     = (int*)alloc((size_t)HTOT * 4);
  int* offA     = (int*)alloc((size_t)HTOT * 4);
  int* bsum     = (int*)alloc(1024);
  u16* W1t      = (u16*)alloc((size_t)3 * 512 * 256 * 2);   // transposed W1 for readout1
  u16* pooledb  = (u16*)alloc((size_t)3 * NB * HD * 2);     // bf16 pooled for readout1_mfma
  int* cur      = (int*)pooled;   // scan cursor; pooled dead until pooling

  u16* wtSelf = wt;
  u16* wtUpx  = wt + (size_t)12 * 65536;
  u16* wtUpa  = wt + (size_t)20 * 65536;
  u16* wtB    = wt + (size_t)28 * 65536;
  u16* wtP    = wt + (size_t)36 * 65536;
  u16* wtPref = wt + (size_t)37 * 65536;

  // small converted params in mask_e's 1 MiB (dead after dedup)
  u16* W1c = (u16*)mask_e;
  u16* b1c = W1c + 393216;
  u16* W2c = b1c + 1536;
  u16* b2c = W2c + 5120;
  u16* bsc = b2c + 16;
  u16* bpc = bsc + 3072;

  // ---- prologue
  detect_dtype<<<1, 64, 0, stream>>>((const u16*)x_n, flag);
  // masks are contiguous allocations: one zero pass (1.5 MiB)
  zero_f4<<<(98304 + 255)/256, 256, 0, stream>>>((float*)mask_e, 98304);
  dedup_kernel<<<QE/256, 256, 0, stream>>>(eb_b, eb_i, eb_j, mask_e, valid_e, QE, MAXE, MAXN);
  dedup_kernel<<<QC/256, 256, 0, stream>>>(cb_b, cb_i, cb_j, mask_c, valid_c, QC, MAXC, MAXE);

  wt_all<<<dim3(16,16,38), dim3(16,16), 0, stream>>>(d_in[17], d_in[19], d_in[20],
                                                     d_in[21], d_in[22], d_in[23], wt, flag);
  conv3<<<14336, 256, 0, stream>>>(x_n, xn, x_e, xe, x_c, xc, flag);
  conv_params<<<197, 256, 0, stream>>>(d_in[25], W1c, d_in[26], b1c, d_in[27], W2c,
                                       d_in[28], b2c, d_in[18], bsc, d_in[24], bpc, flag);
  w1_transpose<<<dim3(32,16,3), dim3(16,16), 0, stream>>>(W1c, W1t);

  // ---- CSR build (histogram -> scan -> fill), fused
  zero_f4<<<(HTOT/4 + 255)/256, 256, 0, stream>>>((float*)hist, HTOT/4);
  hist_all<<<PN/256 + PE/256 + QE/256 + QC/256, 256, 0, stream>>>(
      n_up_b, n_up_i, e_up_b, e_up_i, eb_b, eb_i, valid_e, cb_b, cb_i, valid_c, hist);
  scan1<<<HTOT/1024, 256, 0, stream>>>(hist, bsum);
  scan2<<<1, 256, 0, stream>>>(bsum, HTOT/1024);
  scan3<<<HTOT/1024, 256, 0, stream>>>(hist, bsum, offA, cur);
  fill_all<<<PN/256 + PE/256 + QE/256 + QC/256, 256, 0, stream>>>(
      n_up_b, n_up_i, n_up_j, n_up_e, e_up_b, e_up_i, e_up_j, e_up_c,
      eb_b, eb_i, eb_j, valid_e, cb_b, cb_i, cb_j, valid_c, cur, csrUp, csrBd);

  // ---- layers (9 dispatches each)
  for(int l = 0; l < NLAYER; l++){
    const u16* Wupx0 = wtUpx + (size_t)(l*2+0) * 65536;
    const u16* Wupx1 = wtUpx + (size_t)(l*2+1) * 65536;
    const u16* Wupa0 = wtUpa + (size_t)(l*2+0) * 65536;
    const u16* Wupa1 = wtUpa + (size_t)(l*2+1) * 65536;
    const u16* Wb0   = wtB   + (size_t)(l*2+0) * 65536;
    const u16* Wb1   = wtB   + (size_t)(l*2+1) * 65536;
    const u16* Ws0   = wtSelf + (size_t)(l*3+0) * 65536;
    const u16* Ws1   = wtSelf + (size_t)(l*3+1) * 65536;
    const u16* Ws2   = wtSelf + (size_t)(l*3+2) * 65536;
    const u16* bs0 = bsc + (size_t)(l*3+0) * HD;
    const u16* bs1 = bsc + (size_t)(l*3+1) * HD;
    const u16* bs2 = bsc + (size_t)(l*3+2) * HD;

    // nodes: {Yn(SMa), Ze(BIG1), BDn(SMb)} from OLD xn/xe in ONE dispatch
    gemm_k<0><<<MN/64 + ME/64 + MN/64, 512, 0, stream>>>(
        xn, Wupx0, SMa, MN/64, xe, Wupa0, BIG1, ME/64, xn, Wb0, SMb,
        nullptr, nullptr, nullptr, nullptr);
    gather_k<1,0><<<MN/4, 256, 0, stream>>>(SMa, BIG1, nullptr, csrUp, csrBd,
                                            offA, hist, SEG_N, 0, ACC, 0);
    gemm_k<2><<<MN/64, 512, 0, stream>>>(xn, Ws0, xn, MN/64, xn, Ws0, xn, 0, xn, Ws0, xn,
                                         nullptr, nullptr, ACC, bs0);

    // cells: {Zc(SMa, held for edges), BDe(BIG1)} in ONE dispatch
    gemm_k<0><<<MC/64 + ME/64, 512, 0, stream>>>(
        xc, Wupa1, SMa, MC/64, xe, Wb1, BIG1, ME/64, xc, Wupa1, SMa,
        nullptr, nullptr, nullptr, nullptr);
    gather_k<0,1><<<MC/4, 256, 0, stream>>>(nullptr, nullptr, BIG1, csrUp, csrBd,
                                            offA, hist, 0, SEG_CB, ACC, 0);
    gemm_k<2><<<MC/64, 512, 0, stream>>>(xc, Ws2, xc, MC/64, xc, Ws2, xc, 0, xc, Ws2, xc,
                                         nullptr, nullptr, ACC, bs2);

    // edges: Ye(BIG1) from OLD xe; full-width gather + fused self
    gemm_k<0><<<ME/64, 512, 0, stream>>>(
        xe, Wupx1, BIG1, ME/64, xe, Wupx1, BIG1, 0, xe, Wupx1, BIG1,
        nullptr, nullptr, nullptr, nullptr);
    gather_k<1,1><<<ME/4, 256, 0, stream>>>(BIG1, SMa, SMb, csrUp, csrBd,
                                            offA, hist, SEG_E, SEG_EB, ACC, 0);
    gemm_k<2><<<ME/64, 512, 0, stream>>>(xe, Ws1, xe, ME/64, xe, Ws1, xe, 0, xe, Ws1, xe,
                                         nullptr, nullptr, ACC, bs1);
  }

  // ---- gated pooling: REFs into SMa/ACC/SMb, ONE segmented dual-A GEMM
  // (G aliases REF: per-block A2 rows fully staged before C rows written),
  // then one fused pool_all.
  conv3<<<14336, 256, 0, stream>>>(x_n, SMa, x_e, ACC, x_c, SMb, flag);
  {
    long np4 = (long)3 * NB * HD / 4;
    zero_f4<<<(int)((np4 + 255)/256), 256, 0, stream>>>(pooled, np4);
  }
  gemm_k<3><<<MN/64 + ME/64 + MC/64, 512, 0, stream>>>(
      xn, SMa, SMa, MN/64, xe, ACC, ACC, ME/64, xc, SMb, SMb,
      wtP, wtPref, nullptr, nullptr);
  pool_all<<<dim3(NB, 7), 256, 0, stream>>>(SMa, ACC, SMb, bpc, xn, xe, xc, pooled);

  // ---- readout
  conv_f2b<<<96, 256, 0, stream>>>(pooled, pooledb, (long)3 * NB * HD);
  readout1_mfma<<<dim3(2,2), 512, 0, stream>>>(pooledb, W1t, b1c, hbuf);
  readout2<<<NB, 64, 0, stream>>>(hbuf, W2c, b2c, d_out, flag);
}

// Round 10
// 1251.801 us; speedup vs baseline: 1.0709x; 1.0029x over previous
//
#include <hip/hip_runtime.h>
#include <cstdint>
#include <cstddef>

typedef unsigned short u16;
typedef __bf16 bf16x8 __attribute__((ext_vector_type(8)));
typedef float f32x4 __attribute__((ext_vector_type(4)));
typedef unsigned short u16x8 __attribute__((ext_vector_type(8)));

#define NB   256
#define MAXN 128
#define MAXE 256
#define MAXC 64
#define HD   256
#define NLAYER 4
#define PN 131072
#define PE 98304
#define QE 131072
#define QC 65536
#define MN (NB*MAXN)   /* 32768 node rows  */
#define ME (NB*MAXE)   /* 65536 edge rows  */
#define MC (NB*MAXC)   /* 16384 cell rows  */

// CSR segment bases in the concatenated histogram/offset arrays
#define SEG_N  0
#define SEG_E  (MN)
#define SEG_EB (MN + ME)
#define SEG_CB (MN + 2*ME)
#define HTOT   (MN + 2*ME + MC)      /* 229376, divisible by 1024 */
#define UPTOT  (PN + PE)             /* csrBd global-index base   */

__device__ __forceinline__ float bf2f(u16 u){
  union{unsigned int i; float f;} x; x.i = ((unsigned int)u) << 16; return x.f;
}
__device__ __forceinline__ u16 f2bf(float f){
  union{float f; unsigned int i;} x; x.f = f;
  unsigned int r = x.i + 0x7fffu + ((x.i >> 16) & 1u);
  return (u16)(r >> 16);
}
__device__ __forceinline__ f32x4 MFMA(bf16x8 a, bf16x8 b, f32x4 c){
  return __builtin_amdgcn_mfma_f32_16x16x32_bf16(a, b, c, 0, 0, 0);
}
// async global->LDS, 16B per lane; lds base wave-uniform (lane*16 implicit)
__device__ __forceinline__ void gl_lds16(const u16* g, u16* l){
  __builtin_amdgcn_global_load_lds(
      (const __attribute__((address_space(1))) unsigned int*)g,
      (__attribute__((address_space(3))) unsigned int*)l, 16, 0, 0);
}

// ---------------- dtype sniff (bf16 vs f32 input buffers)
__global__ void detect_dtype(const u16* __restrict__ x, int* __restrict__ flag){
  if(threadIdx.x == 0 && blockIdx.x == 0){
    int cnt = 0;
    for(int i = 0; i < 64; i++){
      int e = (x[i] >> 7) & 0xFF;
      if(e >= 118 && e <= 136) cnt++;
    }
    *flag = (cnt >= 50) ? 1 : 0;   // 1 = bf16, 0 = f32
  }
}

// ---------------- conv helper: one 8-elem unit at offset i of span (s,d,n)
__device__ __forceinline__ void convSpan(const void* s, u16* d, long n, long i, int isbf){
  if(i + 8 <= n){
    if(isbf){
      *reinterpret_cast<u16x8*>(d + i) = *reinterpret_cast<const u16x8*>((const u16*)s + i);
    }else{
      const float* sp = (const float*)s + i;
      float4 a = *reinterpret_cast<const float4*>(sp);
      float4 b = *reinterpret_cast<const float4*>(sp + 4);
      u16x8 o;
      o[0]=f2bf(a.x); o[1]=f2bf(a.y); o[2]=f2bf(a.z); o[3]=f2bf(a.w);
      o[4]=f2bf(b.x); o[5]=f2bf(b.y); o[6]=f2bf(b.z); o[7]=f2bf(b.w);
      *reinterpret_cast<u16x8*>(d + i) = o;
    }
  }else{
    for(long e = i; e < n; e++)
      d[e] = isbf ? ((const u16*)s)[e] : f2bf(((const float*)s)[e]);
  }
}

// ---------------- fused 3-target feature conversion (n/e/c shapes fixed)
__global__ __launch_bounds__(256) void conv3(const void* __restrict__ s0, u16* __restrict__ d0,
                                             const void* __restrict__ s1, u16* __restrict__ d1,
                                             const void* __restrict__ s2, u16* __restrict__ d2,
                                             const int* __restrict__ flag){
  const long U0 = (long)MN * HD / 8, U1 = (long)ME * HD / 8, U2 = (long)MC * HD / 8;
  long u = (long)blockIdx.x * 256 + threadIdx.x;
  const int isbf = *flag;
  if(u < U0){ convSpan(s0, d0, (long)MN * HD, u * 8, isbf); return; }
  u -= U0;
  if(u < U1){ convSpan(s1, d1, (long)ME * HD, u * 8, isbf); return; }
  u -= U1;
  if(u < U2) convSpan(s2, d2, (long)MC * HD, u * 8, isbf);
}

// ---------------- fused small-parameter conversion (6 spans)
__global__ __launch_bounds__(256) void conv_params(
    const void* sW1, u16* dW1, const void* sb1, u16* db1,
    const void* sW2, u16* dW2, const void* sb2, u16* db2,
    const void* sbs, u16* dbs, const void* sbp, u16* dbp,
    const int* __restrict__ flag){
  long u = (long)blockIdx.x * 256 + threadIdx.x;
  const int isbf = *flag;
  if(u < 49152){ convSpan(sW1, dW1, 393216, u * 8, isbf); return; } u -= 49152;
  if(u < 192)  { convSpan(sb1, db1, 1536,   u * 8, isbf); return; } u -= 192;
  if(u < 640)  { convSpan(sW2, dW2, 5120,   u * 8, isbf); return; } u -= 640;
  if(u < 2)    { convSpan(sb2, db2, 10,     u * 8, isbf); return; } u -= 2;
  if(u < 384)  { convSpan(sbs, dbs, 3072,   u * 8, isbf); return; } u -= 384;
  if(u < 32)     convSpan(sbp, dbp, 256,    u * 8, isbf);
}

// ---------------- f32 -> bf16 (always f32 source; for pooled)
__global__ __launch_bounds__(256) void conv_f2b(const float* __restrict__ s, u16* __restrict__ d, long n){
  long i = ((long)blockIdx.x * 256 + threadIdx.x) * 8;
  if(i >= n) return;
  float4 a = *reinterpret_cast<const float4*>(s + i);
  float4 b = *reinterpret_cast<const float4*>(s + i + 4);
  u16x8 o;
  o[0]=f2bf(a.x); o[1]=f2bf(a.y); o[2]=f2bf(a.z); o[3]=f2bf(a.w);
  o[4]=f2bf(b.x); o[5]=f2bf(b.y); o[6]=f2bf(b.z); o[7]=f2bf(b.w);
  *reinterpret_cast<u16x8*>(d + i) = o;
}

// ---------------- zero fill
__global__ __launch_bounds__(256) void zero_f4(float* __restrict__ p, long n4){
  long i = (long)blockIdx.x * blockDim.x + threadIdx.x;
  if(i >= n4) return;
  float4 z = {0.f, 0.f, 0.f, 0.f};
  *reinterpret_cast<float4*>(p + i * 4) = z;
}

// ---------------- fused weight transpose: 38 [256,256] slices -> bf16 [n*256+k]
// z<12: Wself, z<20: Wupx, z<28: Wupa, z<36: Wb, z==36: Wp, z==37: Wp_ref
__global__ void wt_all(const void* __restrict__ pSelf, const void* __restrict__ pUpx,
                       const void* __restrict__ pUpa, const void* __restrict__ pB,
                       const void* __restrict__ pP, const void* __restrict__ pPref,
                       u16* __restrict__ wt, const int* __restrict__ flag){
  __shared__ u16 t[16][17];
  int z = blockIdx.z;
  const void* src; int m; u16* dst;
  if(z < 12)      { src = pSelf; m = z;      dst = wt; }
  else if(z < 20) { src = pUpx;  m = z - 12; dst = wt + (size_t)12 * 65536; }
  else if(z < 28) { src = pUpa;  m = z - 20; dst = wt + (size_t)20 * 65536; }
  else if(z < 36) { src = pB;    m = z - 28; dst = wt + (size_t)28 * 65536; }
  else if(z == 36){ src = pP;    m = 0;      dst = wt + (size_t)36 * 65536; }
  else            { src = pPref; m = 0;      dst = wt + (size_t)37 * 65536; }
  int n0 = blockIdx.x * 16, k0 = blockIdx.y * 16;
  size_t sidx = (size_t)m * 65536 + (size_t)(k0 + threadIdx.y) * 256 + n0 + threadIdx.x;
  u16 v = (*flag) ? ((const u16*)src)[sidx] : f2bf(((const float*)src)[sidx]);
  t[threadIdx.y][threadIdx.x] = v;
  __syncthreads();
  dst[(size_t)m * 65536 + (size_t)(n0 + threadIdx.y) * 256 + (k0 + threadIdx.x)] =
      t[threadIdx.x][threadIdx.y];
}

// ---------------- W1 transpose: src bf16 [3][256 k][512 o] -> dst [3][512 o][256 k]
__global__ void w1_transpose(const u16* __restrict__ src, u16* __restrict__ dst){
  __shared__ u16 t[16][17];
  int i = blockIdx.z;
  int o0 = blockIdx.x * 16, k0 = blockIdx.y * 16;
  t[threadIdx.y][threadIdx.x] =
      src[(size_t)i * 131072 + (size_t)(k0 + threadIdx.y) * 512 + o0 + threadIdx.x];
  __syncthreads();
  dst[(size_t)i * 131072 + (size_t)(o0 + threadIdx.y) * 256 + (k0 + threadIdx.x)] =
      t[threadIdx.x][threadIdx.y];
}

// ---------------- dedup boundary incidences (.set(1.0): idempotent)
__global__ void dedup_kernel(const int* __restrict__ bb, const int* __restrict__ bi,
                             const int* __restrict__ bj, unsigned int* __restrict__ mask,
                             unsigned char* __restrict__ valid, int Q, int maxI, int maxJ){
  int q = blockIdx.x * blockDim.x + threadIdx.x;
  if(q >= Q) return;
  int s = (bb[q] * maxI + bi[q]) * maxJ + bj[q];
  unsigned int bit = 1u << (s & 31);
  unsigned int old = atomicOr(&mask[s >> 5], bit);
  valid[q] = (old & bit) ? 0 : 1;
}

// ---------------- fused CSR histogram over all 4 segments
__global__ __launch_bounds__(256) void hist_all(
    const int* __restrict__ nub, const int* __restrict__ nui,
    const int* __restrict__ eub, const int* __restrict__ eui,
    const int* __restrict__ ebb, const int* __restrict__ ebi, const unsigned char* __restrict__ ve,
    const int* __restrict__ cbb, const int* __restrict__ cbi, const unsigned char* __restrict__ vc,
    int* __restrict__ hist){
  int bx = blockIdx.x, t = threadIdx.x;
  if(bx < PN/256){
    int p = bx * 256 + t;
    atomicAdd(&hist[SEG_N + nub[p] * MAXN + nui[p]], 1);
  }else if(bx < PN/256 + PE/256){
    int p = (bx - PN/256) * 256 + t;
    atomicAdd(&hist[SEG_E + eub[p] * MAXE + eui[p]], 1);
  }else if(bx < PN/256 + PE/256 + QE/256){
    int q = (bx - PN/256 - PE/256) * 256 + t;
    if(ve[q]) atomicAdd(&hist[SEG_EB + ebb[q] * MAXE + ebi[q]], 1);
  }else{
    int q = (bx - PN/256 - PE/256 - QE/256) * 256 + t;
    if(vc[q]) atomicAdd(&hist[SEG_CB + cbb[q] * MAXC + cbi[q]], 1);
  }
}

// ---------------- 3-phase exclusive scan over HTOT ints (1024 elems / block)
__global__ __launch_bounds__(256) void scan1(const int* __restrict__ hist, int* __restrict__ bsum){
  __shared__ int s[256];
  int t = threadIdx.x;
  long base = (long)blockIdx.x * 1024 + t * 4;
  int4 v = *reinterpret_cast<const int4*>(hist + base);
  s[t] = v.x + v.y + v.z + v.w;
  __syncthreads();
  for(int st = 128; st > 0; st >>= 1){
    if(t < st) s[t] += s[t + st];
    __syncthreads();
  }
  if(t == 0) bsum[blockIdx.x] = s[0];
}
__global__ __launch_bounds__(256) void scan2(int* __restrict__ bsum, int nb){
  __shared__ int s[256];
  int t = threadIdx.x;
  int v = (t < nb) ? bsum[t] : 0;
  s[t] = v;
  __syncthreads();
  for(int st = 1; st < 256; st <<= 1){
    int u = (t >= st) ? s[t - st] : 0;
    __syncthreads();
    s[t] += u;
    __syncthreads();
  }
  if(t < nb) bsum[t] = s[t] - v;   // exclusive
}
__global__ __launch_bounds__(256) void scan3(const int* __restrict__ hist, const int* __restrict__ bsum,
                                             int* __restrict__ off, int* __restrict__ cur){
  __shared__ int s[256];
  int t = threadIdx.x;
  long base = (long)blockIdx.x * 1024 + t * 4;
  int4 v = *reinterpret_cast<const int4*>(hist + base);
  int sum = v.x + v.y + v.z + v.w;
  s[t] = sum;
  __syncthreads();
  for(int st = 1; st < 256; st <<= 1){
    int u = (t >= st) ? s[t - st] : 0;
    __syncthreads();
    s[t] += u;
    __syncthreads();
  }
  int excl = s[t] - sum + bsum[blockIdx.x];
  int4 o;
  o.x = excl; o.y = o.x + v.x; o.z = o.y + v.y; o.w = o.z + v.z;
  *reinterpret_cast<int4*>(off + base) = o;
  *reinterpret_cast<int4*>(cur + base) = o;
}

// ---------------- fused CSR fill over all 4 segments
__global__ __launch_bounds__(256) void fill_all(
    const int* __restrict__ nub, const int* __restrict__ nui,
    const int* __restrict__ nuj, const int* __restrict__ nue,
    const int* __restrict__ eub, const int* __restrict__ eui,
    const int* __restrict__ euj, const int* __restrict__ euc,
    const int* __restrict__ ebb, const int* __restrict__ ebi,
    const int* __restrict__ ebj, const unsigned char* __restrict__ ve,
    const int* __restrict__ cbb, const int* __restrict__ cbi,
    const int* __restrict__ cbj, const unsigned char* __restrict__ vc,
    int* __restrict__ cur, int2* __restrict__ csrUp, int* __restrict__ csrBd){
  int bx = blockIdx.x, t = threadIdx.x;
  if(bx < PN/256){
    int p = bx * 256 + t; int b = nub[p];
    int pos = atomicAdd(&cur[SEG_N + b * MAXN + nui[p]], 1);
    int2 e; e.x = b * MAXN + nuj[p]; e.y = b * MAXE + nue[p];
    csrUp[pos] = e;
  }else if(bx < PN/256 + PE/256){
    int p = (bx - PN/256) * 256 + t; int b = eub[p];
    int pos = atomicAdd(&cur[SEG_E + b * MAXE + eui[p]], 1);
    int2 e; e.x = b * MAXE + euj[p]; e.y = b * MAXC + euc[p];
    csrUp[pos] = e;
  }else if(bx < PN/256 + PE/256 + QE/256){
    int q = (bx - PN/256 - PE/256) * 256 + t;
    if(!ve[q]) return;
    int b = ebb[q];
    int pos = atomicAdd(&cur[SEG_EB + b * MAXE + ebi[q]], 1);
    csrBd[pos - UPTOT] = b * MAXN + ebj[q];
  }else{
    int q = (bx - PN/256 - PE/256 - QE/256) * 256 + t;
    if(!vc[q]) return;
    int b = cbb[q];
    int pos = atomicAdd(&cur[SEG_CB + b * MAXC + cbi[q]], 1);
    csrBd[pos - UPTOT] = b * MAXE + cbj[q];
  }
}

// ---------------- gather: one wave per receiver row; bf16 ACC store; XCD swizzle.
// v2: depth-2 neighbor prefetch (issue k+1's csr entry + feature rows before
// consuming k's) to hide the dependent-load chain latency per neighbor.
template<int HAS_UP, int HAS_BD>
__global__ __launch_bounds__(256) void gather_k(
    const u16* __restrict__ Y, const u16* __restrict__ Z, const u16* __restrict__ BD,
    const int2* __restrict__ csrUp, const int* __restrict__ csrBd,
    const int* __restrict__ off, const int* __restrict__ deg,
    int upBase, int bdBase, u16* __restrict__ ACC, int rowLo){
  const int nb = gridDim.x;
  int bx = blockIdx.x;
  if((nb & 7) == 0) bx = (bx & 7) * (nb >> 3) + (bx >> 3);   // XCD-contiguous ranges
  const int row = rowLo + bx * 4 + (threadIdx.x >> 6);
  const int lane = threadIdx.x & 63;
  const int c = lane * 4;
  float a0 = 0.f, a1 = 0.f, a2 = 0.f, a3 = 0.f;
  if(HAS_UP){
    int s = off[upBase + row];
    int d = deg[upBase + row];
    if(d > 0){
      int2 e = csrUp[s];
      ushort4 y0 = *reinterpret_cast<const ushort4*>(Y + (size_t)e.x * 256 + c);
      ushort4 z0 = *reinterpret_cast<const ushort4*>(Z + (size_t)e.y * 256 + c);
      for(int k = 1; k <= d; k++){
        ushort4 y1 = y0, z1 = z0;
        if(k < d){
          int2 e2 = csrUp[s + k];
          y1 = *reinterpret_cast<const ushort4*>(Y + (size_t)e2.x * 256 + c);
          z1 = *reinterpret_cast<const ushort4*>(Z + (size_t)e2.y * 256 + c);
        }
        a0 += fmaxf(bf2f(y0.x) + bf2f(z0.x), 0.f);
        a1 += fmaxf(bf2f(y0.y) + bf2f(z0.y), 0.f);
        a2 += fmaxf(bf2f(y0.z) + bf2f(z0.z), 0.f);
        a3 += fmaxf(bf2f(y0.w) + bf2f(z0.w), 0.f);
        y0 = y1; z0 = z1;
      }
    }
  }
  if(HAS_BD){
    int s = off[bdBase + row] - UPTOT;
    int d = deg[bdBase + row];
    if(d > 0){
      int j = csrBd[s];
      ushort4 x0 = *reinterpret_cast<const ushort4*>(BD + (size_t)j * 256 + c);
      for(int k = 1; k <= d; k++){
        ushort4 x1 = x0;
        if(k < d){
          int j2 = csrBd[s + k];
          x1 = *reinterpret_cast<const ushort4*>(BD + (size_t)j2 * 256 + c);
        }
        a0 += bf2f(x0.x); a1 += bf2f(x0.y); a2 += bf2f(x0.z); a3 += bf2f(x0.w);
        x0 = x1;
      }
    }
  }
  ushort4 o; o.x = f2bf(a0); o.y = f2bf(a1); o.z = f2bf(a2); o.w = f2bf(a3);
  *reinterpret_cast<ushort4*>(ACC + (size_t)(row - rowLo) * 256 + c) = o;
}

// ---------------- LDS-staged bf16 MFMA GEMM, v8: r9 8-wave BK=64 core with
// SINGLE-buffered lB (weight slices are L2-resident, ~300cy; their restage
// is issued right after the consume-barrier and has a full compute phase to
// land) + double-buffered lA (HBM latency, depth-2). LDS 48 KiB ->
// 3 blocks/CU, 24 waves/CU (r9 measured: occupancy is the binding axis --
// 34% occ, no pipe >25%). Per stage-round: issue B(t+1) (4 loads) then
// A(t+2) (1 load, newest); pre-compute wait vmcnt(1) (B(t),A(t) landed,
// A(t+1) in flight), vmcnt(0) only at last tile. Proven r&7 XOR swizzle
// both-sides; operand-swapped MFMA -> ushort4 8B epilogue. Segmented grid.
// MODE 0: C = P@Q.
// MODE 2: C = relu(P@Q + ACCbf + bias), C may alias P.   (single segment)
// MODE 3: C = P@S1 + Q@S2  (P=x, Q=ref, shared weights). C may alias Q.
template<int MODE>
__global__ __launch_bounds__(512) void gemm_k(
    const u16* P0, const u16* Q0, u16* C0, int n0,
    const u16* P1, const u16* Q1, u16* C1, int n1,
    const u16* P2, const u16* Q2, u16* C2,
    const u16* __restrict__ S1, const u16* __restrict__ S2,
    const u16* __restrict__ ACC, const u16* __restrict__ bias){
  __shared__ u16 lA[2][64 * 64];    // double-buffered A   16 KiB
  __shared__ u16 lB[256 * 64];      // single-buffered B   32 KiB (L2-hit restage)
  int bx = blockIdx.x;
  const u16* P = P0; const u16* Q = Q0; u16* C = C0;
  if(bx >= n0 + n1){ bx -= n0 + n1; P = P2; Q = Q2; C = C2; }
  else if(bx >= n0){ bx -= n0;      P = P1; Q = Q1; C = C1; }
  const int t = threadIdx.x;
  const int lane = t & 63, wv = t >> 6;   // 8 waves; each: 64 rows x 32 cols
  const int r = lane & 15, q = lane >> 4;
  const int rsw = r & 7;                   // read-side XOR key (row&7), proven
  const size_t m0 = (size_t)bx * 64;
  const int lrow = lane >> 3, lchk = lane & 7;
  const int csw = lchk ^ lrow;             // source chunk pre-swizzle (lrow==row&7)

  f32x4 acc[4][2];
#pragma unroll
  for(int i = 0; i < 4; i++)
#pragma unroll
    for(int j = 0; j < 2; j++) acc[i][j] = {0.f, 0.f, 0.f, 0.f};

  const int NT = (MODE == 3) ? 8 : 4;      // tiles: (src, k0) flattened

  auto stageA = [&](int tt, int buf){
    const u16* Ap = (MODE == 3) ? ((tt >= 4) ? Q : P) : P;
    const int k0 = (tt & 3) * 64;
    gl_lds16(Ap + (m0 + wv * 8 + lrow) * 256 + k0 + csw * 8,
             &lA[buf][(wv * 8) * 64]);
  };
  auto stageB = [&](int tt){
    const u16* Wp = (MODE == 3) ? ((tt >= 4) ? S2 : S1) : Q;
    const int k0 = (tt & 3) * 64;
#pragma unroll
    for(int j = 0; j < 4; j++){
      const int n = wv * 32 + j * 8 + lrow;
      gl_lds16(Wp + (size_t)n * 256 + k0 + csw * 8,
               &lB[(wv * 32 + j * 8) * 64]);
    }
  };

  // prologue: B(0), A(0); A(1) issued LAST (it's the one allowed to fly)
  stageB(0);
  stageA(0, 0);
  stageA(1, 1);

#pragma unroll
  for(int tt = 0; tt < NT; tt++){
    const int cur = tt & 1;
    // need B(tt)+A(tt) landed; A(tt+1) (newest) may stay in flight
    if(tt < NT - 1) asm volatile("s_waitcnt vmcnt(1)" ::: "memory");
    else            asm volatile("s_waitcnt vmcnt(0)" ::: "memory");
    __builtin_amdgcn_s_barrier();
    __builtin_amdgcn_s_setprio(1);
#pragma unroll
    for(int ks = 0; ks < 2; ks++){
      bf16x8 af[4], bfr[2];
#pragma unroll
      for(int i = 0; i < 4; i++)
        af[i] = *reinterpret_cast<const bf16x8*>(
            &lA[cur][(i * 16 + r) * 64 + (((ks * 4 + q) ^ rsw) * 8)]);
#pragma unroll
      for(int j = 0; j < 2; j++)
        bfr[j] = *reinterpret_cast<const bf16x8*>(
            &lB[(wv * 32 + j * 16 + r) * 64 + (((ks * 4 + q) ^ rsw) * 8)]);
      // operand-swapped: D[row<-n][col<-m]; per thread n = q*4+reg, m = r
#pragma unroll
      for(int i = 0; i < 4; i++)
#pragma unroll
        for(int j = 0; j < 2; j++) acc[i][j] = MFMA(bfr[j], af[i], acc[i][j]);
    }
    __builtin_amdgcn_s_setprio(0);
    __builtin_amdgcn_s_barrier();   // all waves done reading lB / lA[cur]
    if(tt + 1 < NT) stageB(tt + 1);       // L2-hit restage, lands within phase
    if(tt + 2 < NT) stageA(tt + 2, cur);  // HBM prefetch, depth-2 (newest)
  }

  // epilogue (swapped layout): row = m0 + i*16 + r, col = wv*32 + j*16 + q*4 + reg
#pragma unroll
  for(int i = 0; i < 4; i++){
    const size_t row = m0 + i * 16 + r;
#pragma unroll
    for(int j = 0; j < 2; j++){
      const int col = wv * 32 + j * 16 + q * 4;
      const size_t idx = row * 256 + col;
      f32x4 v = acc[i][j];
      ushort4 o;
      if(MODE == 2){
        const ushort4 a4 = *reinterpret_cast<const ushort4*>(ACC + idx);
        const ushort4 b4 = *reinterpret_cast<const ushort4*>(bias + col);
        o.x = f2bf(fmaxf(v[0] + bf2f(a4.x) + bf2f(b4.x), 0.f));
        o.y = f2bf(fmaxf(v[1] + bf2f(a4.y) + bf2f(b4.y), 0.f));
        o.z = f2bf(fmaxf(v[2] + bf2f(a4.z) + bf2f(b4.z), 0.f));
        o.w = f2bf(fmaxf(v[3] + bf2f(a4.w) + bf2f(b4.w), 0.f));
      }else{
        o.x = f2bf(v[0]); o.y = f2bf(v[1]); o.z = f2bf(v[2]); o.w = f2bf(v[3]);
      }
      *reinterpret_cast<ushort4*>(C + idx) = o;
    }
  }
}

// ---------------- fused gated pooling reduce over all 3 dims
// grid (NB, 7): y<2 -> nodes (2 chunks), y<6 -> edges (4 chunks), y==6 -> cells.
__global__ __launch_bounds__(256) void pool_all(
    const u16* __restrict__ Gn, const u16* __restrict__ Ge, const u16* __restrict__ Gc,
    const u16* __restrict__ bpv,
    const u16* __restrict__ Xn, const u16* __restrict__ Xe, const u16* __restrict__ Xc,
    float* __restrict__ pooled){
  int b = blockIdx.x, h = threadIdx.x, y = blockIdx.y;
  const u16 *G, *X; float* out; int maxR, r0;
  if(y < 2)      { G = Gn; X = Xn; out = pooled;                    maxR = MAXN; r0 = y * 64; }
  else if(y < 6) { G = Ge; X = Xe; out = pooled + (size_t)NB * HD;  maxR = MAXE; r0 = (y - 2) * 64; }
  else           { G = Gc; X = Xc; out = pooled + (size_t)2*NB*HD;  maxR = MAXC; r0 = 0; }
  float bias = bf2f(bpv[h]);
  float acc = 0.f;
  for(int r = r0; r < r0 + 64; r++){
    size_t o = ((size_t)b * maxR + r) * 256 + h;
    float t = bf2f(G[o]) + bias;
    float w = 1.f / (1.f + __expf(-t));
    acc += w * bf2f(X[o]);
  }
  atomicAdd(&out[b * 256 + h], acc);
}

// ---------------- readout1 as MFMA GEMM (swapped-operand layout)
__global__ __launch_bounds__(512) void readout1_mfma(const u16* __restrict__ Ab,
                                                     const u16* __restrict__ W1t,
                                                     const u16* __restrict__ b1,
                                                     float* __restrict__ hbuf){
  __shared__ u16 lA[2][128 * 64];
  __shared__ u16 lB[2][256 * 64];
  const int t = threadIdx.x;
  const int lane = t & 63, wv = t >> 6;
  const int wm = wv >> 2, wn = wv & 3;      // 2 x 4 wave grid, each 64x64
  const int r = lane & 15, q = lane >> 4;
  const int rsw = r & 7;
  const int b0 = blockIdx.x * 128;
  const int o0 = blockIdx.y * 256;
  const int lrow = lane >> 3, lchk = lane & 7;
  const int csw = lchk ^ lrow;

  f32x4 acc[4][4], facc[4][4];
#pragma unroll
  for(int i = 0; i < 4; i++)
#pragma unroll
    for(int j = 0; j < 4; j++){ acc[i][j] = {0.f,0.f,0.f,0.f}; facc[i][j] = {0.f,0.f,0.f,0.f}; }

  auto stage = [&](int tt, int buf){
    const int ii = tt >> 2, k0 = (tt & 3) * 64;
    const u16* Ap = Ab + (size_t)ii * 65536;
    const u16* Wp = W1t + (size_t)ii * 131072;
#pragma unroll
    for(int i = 0; i < 2; i++){
      const int row = i * 64 + wv * 8 + lrow;
      gl_lds16(Ap + (size_t)(b0 + row) * 256 + k0 + csw * 8, &lA[buf][(i * 64 + wv * 8) * 64]);
    }
#pragma unroll
    for(int j = 0; j < 4; j++){
      const int n = j * 64 + wv * 8 + lrow;
      gl_lds16(Wp + (size_t)(o0 + n) * 256 + k0 + csw * 8, &lB[buf][(j * 64 + wv * 8) * 64]);
    }
  };

  stage(0, 0);
  stage(1, 1);

#pragma unroll
  for(int tt = 0; tt < 12; tt++){
    const int cur = tt & 1;
    if(tt < 11) asm volatile("s_waitcnt vmcnt(6)" ::: "memory");
    else        asm volatile("s_waitcnt vmcnt(0)" ::: "memory");
    __builtin_amdgcn_s_barrier();
#pragma unroll
    for(int ks = 0; ks < 2; ks++){
      bf16x8 af[4], bfr[4];
#pragma unroll
      for(int i = 0; i < 4; i++)
        af[i] = *reinterpret_cast<const bf16x8*>(
            &lA[cur][(wm * 64 + i * 16 + r) * 64 + (((ks * 4 + q) ^ rsw) * 8)]);
#pragma unroll
      for(int j = 0; j < 4; j++)
        bfr[j] = *reinterpret_cast<const bf16x8*>(
            &lB[cur][(wn * 64 + j * 16 + r) * 64 + (((ks * 4 + q) ^ rsw) * 8)]);
#pragma unroll
      for(int i = 0; i < 4; i++)
#pragma unroll
        for(int j = 0; j < 4; j++) acc[i][j] = MFMA(bfr[j], af[i], acc[i][j]);
    }
    if((tt & 3) == 3){   // i boundary: relu-flush into facc (registers only)
      const int ib = tt >> 2;
#pragma unroll
      for(int i = 0; i < 4; i++)
#pragma unroll
        for(int j = 0; j < 4; j++){
          const int col = o0 + wn * 64 + j * 16 + q * 4;
          const ushort4 b4 = *reinterpret_cast<const ushort4*>(b1 + ib * 512 + col);
          facc[i][j][0] += fmaxf(acc[i][j][0] + bf2f(b4.x), 0.f);
          facc[i][j][1] += fmaxf(acc[i][j][1] + bf2f(b4.y), 0.f);
          facc[i][j][2] += fmaxf(acc[i][j][2] + bf2f(b4.z), 0.f);
          facc[i][j][3] += fmaxf(acc[i][j][3] + bf2f(b4.w), 0.f);
          acc[i][j] = {0.f, 0.f, 0.f, 0.f};
        }
    }
    __builtin_amdgcn_s_barrier();
    if(tt + 2 < 12) stage(tt + 2, cur);
  }

  // swapped layout: row = b0 + wm*64 + i*16 + r, col = o0 + wn*64 + j*16 + q*4
#pragma unroll
  for(int i = 0; i < 4; i++){
    const int row = b0 + wm * 64 + i * 16 + r;
#pragma unroll
    for(int j = 0; j < 4; j++){
      const int col = o0 + wn * 64 + j * 16 + q * 4;
      *reinterpret_cast<f32x4*>(hbuf + (size_t)row * 512 + col) = facc[i][j];
    }
  }
}

// ---------------- out = h @ W2 + b2 (dtype-matched store)
__global__ __launch_bounds__(64) void readout2(const float* __restrict__ hbuf, const u16* __restrict__ W2,
                                               const u16* __restrict__ b2, void* __restrict__ out,
                                               const int* __restrict__ flag){
  int b = blockIdx.x, o = threadIdx.x;
  if(o >= 10) return;
  float a = bf2f(b2[o]);
  for(int k = 0; k < 512; k++) a += hbuf[(size_t)b * 512 + k] * bf2f(W2[k * 10 + o]);
  if(*flag) ((u16*)out)[b * 10 + o] = f2bf(a);
  else      ((float*)out)[b * 10 + o] = a;
}

extern "C" void kernel_launch(void* const* d_in, const int* in_sizes, int n_in,
                              void* d_out, int out_size, void* d_ws, size_t ws_size,
                              hipStream_t stream){
  const void* x_n = d_in[0];
  const void* x_e = d_in[1];
  const void* x_c = d_in[2];
  const int* n_up_b = (const int*)d_in[3];
  const int* n_up_i = (const int*)d_in[4];
  const int* n_up_j = (const int*)d_in[5];
  const int* n_up_e = (const int*)d_in[6];
  const int* e_up_b = (const int*)d_in[7];
  const int* e_up_i = (const int*)d_in[8];
  const int* e_up_j = (const int*)d_in[9];
  const int* e_up_c = (const int*)d_in[10];
  const int* eb_b = (const int*)d_in[11];
  const int* eb_i = (const int*)d_in[12];
  const int* eb_j = (const int*)d_in[13];
  const int* cb_b = (const int*)d_in[14];
  const int* cb_i = (const int*)d_in[15];
  const int* cb_j = (const int*)d_in[16];

  // ---- workspace carve-up (~174 MiB)
  char* base = (char*)d_ws; size_t off0 = 0;
  auto alloc = [&](size_t n)->char*{ char* p = base + off0; off0 = (off0 + n + 255) & ~(size_t)255; return p; };
  u16* xn = (u16*)alloc((size_t)MN * HD * 2);
  u16* xe = (u16*)alloc((size_t)ME * HD * 2);
  u16* xc = (u16*)alloc((size_t)MC * HD * 2);
  u16* BIG1 = (u16*)alloc((size_t)ME * HD * 2);      // Ze/BDe/Ye staging
  u16* SMa  = (u16*)alloc((size_t)MN * HD * 2);      // Yn then Zc; pool: REFn/Gn
  u16* SMb  = (u16*)alloc((size_t)MN * HD * 2);      // BDn; pool: REFc/Gc
  u16* ACC  = (u16*)alloc((size_t)ME * HD * 2);      // full-width bf16 gather acc; pool: REFe/Ge
  u16* wt = (u16*)alloc((size_t)38 * 65536 * 2);
  unsigned int* mask_e = (unsigned int*)alloc((size_t)NB * MAXE * MAXN / 8);  // dead after dedup -> params
  unsigned int* mask_c = (unsigned int*)alloc((size_t)NB * MAXC * MAXE / 8);
  unsigned char* valid_e = (unsigned char*)alloc(QE);
  unsigned char* valid_c = (unsigned char*)alloc(QC);
  float* pooled = (float*)alloc((size_t)3 * NB * HD * 4);   // also aliased as scan cursor
  float* hbuf   = (float*)alloc((size_t)NB * 512 * 4);
  int* flag     = (int*)alloc(256);
  int2* csrUp   = (int2*)alloc((size_t)UPTOT * 8);
  int* csrBd    = (int*)alloc((size_t)(QE + QC) * 4);
  int* hist     = (int*)alloc((size_t)HTOT * 4);
  int* offA     = (int*)alloc((size_t)HTOT * 4);
  int* bsum     = (int*)alloc(1024);
  u16* W1t      = (u16*)alloc((size_t)3 * 512 * 256 * 2);   // transposed W1 for readout1
  u16* pooledb  = (u16*)alloc((size_t)3 * NB * HD * 2);     // bf16 pooled for readout1_mfma
  int* cur      = (int*)pooled;   // scan cursor; pooled dead until pooling

  u16* wtSelf = wt;
  u16* wtUpx  = wt + (size_t)12 * 65536;
  u16* wtUpa  = wt + (size_t)20 * 65536;
  u16* wtB    = wt + (size_t)28 * 65536;
  u16* wtP    = wt + (size_t)36 * 65536;
  u16* wtPref = wt + (size_t)37 * 65536;

  // small converted params in mask_e's 1 MiB (dead after dedup)
  u16* W1c = (u16*)mask_e;
  u16* b1c = W1c + 393216;
  u16* W2c = b1c + 1536;
  u16* b2c = W2c + 5120;
  u16* bsc = b2c + 16;
  u16* bpc = bsc + 3072;

  // ---- prologue
  detect_dtype<<<1, 64, 0, stream>>>((const u16*)x_n, flag);
  // masks are contiguous allocations: one zero pass (1.5 MiB)
  zero_f4<<<(98304 + 255)/256, 256, 0, stream>>>((float*)mask_e, 98304);
  dedup_kernel<<<QE/256, 256, 0, stream>>>(eb_b, eb_i, eb_j, mask_e, valid_e, QE, MAXE, MAXN);
  dedup_kernel<<<QC/256, 256, 0, stream>>>(cb_b, cb_i, cb_j, mask_c, valid_c, QC, MAXC, MAXE);

  wt_all<<<dim3(16,16,38), dim3(16,16), 0, stream>>>(d_in[17], d_in[19], d_in[20],
                                                     d_in[21], d_in[22], d_in[23], wt, flag);
  conv3<<<14336, 256, 0, stream>>>(x_n, xn, x_e, xe, x_c, xc, flag);
  conv_params<<<197, 256, 0, stream>>>(d_in[25], W1c, d_in[26], b1c, d_in[27], W2c,
                                       d_in[28], b2c, d_in[18], bsc, d_in[24], bpc, flag);
  w1_transpose<<<dim3(32,16,3), dim3(16,16), 0, stream>>>(W1c, W1t);

  // ---- CSR build (histogram -> scan -> fill), fused
  zero_f4<<<(HTOT/4 + 255)/256, 256, 0, stream>>>((float*)hist, HTOT/4);
  hist_all<<<PN/256 + PE/256 + QE/256 + QC/256, 256, 0, stream>>>(
      n_up_b, n_up_i, e_up_b, e_up_i, eb_b, eb_i, valid_e, cb_b, cb_i, valid_c, hist);
  scan1<<<HTOT/1024, 256, 0, stream>>>(hist, bsum);
  scan2<<<1, 256, 0, stream>>>(bsum, HTOT/1024);
  scan3<<<HTOT/1024, 256, 0, stream>>>(hist, bsum, offA, cur);
  fill_all<<<PN/256 + PE/256 + QE/256 + QC/256, 256, 0, stream>>>(
      n_up_b, n_up_i, n_up_j, n_up_e, e_up_b, e_up_i, e_up_j, e_up_c,
      eb_b, eb_i, eb_j, valid_e, cb_b, cb_i, cb_j, valid_c, cur, csrUp, csrBd);

  // ---- layers (9 dispatches each)
  for(int l = 0; l < NLAYER; l++){
    const u16* Wupx0 = wtUpx + (size_t)(l*2+0) * 65536;
    const u16* Wupx1 = wtUpx + (size_t)(l*2+1) * 65536;
    const u16* Wupa0 = wtUpa + (size_t)(l*2+0) * 65536;
    const u16* Wupa1 = wtUpa + (size_t)(l*2+1) * 65536;
    const u16* Wb0   = wtB   + (size_t)(l*2+0) * 65536;
    const u16* Wb1   = wtB   + (size_t)(l*2+1) * 65536;
    const u16* Ws0   = wtSelf + (size_t)(l*3+0) * 65536;
    const u16* Ws1   = wtSelf + (size_t)(l*3+1) * 65536;
    const u16* Ws2   = wtSelf + (size_t)(l*3+2) * 65536;
    const u16* bs0 = bsc + (size_t)(l*3+0) * HD;
    const u16* bs1 = bsc + (size_t)(l*3+1) * HD;
    const u16* bs2 = bsc + (size_t)(l*3+2) * HD;

    // nodes: {Yn(SMa), Ze(BIG1), BDn(SMb)} from OLD xn/xe in ONE dispatch
    gemm_k<0><<<MN/64 + ME/64 + MN/64, 512, 0, stream>>>(
        xn, Wupx0, SMa, MN/64, xe, Wupa0, BIG1, ME/64, xn, Wb0, SMb,
        nullptr, nullptr, nullptr, nullptr);
    gather_k<1,0><<<MN/4, 256, 0, stream>>>(SMa, BIG1, nullptr, csrUp, csrBd,
                                            offA, hist, SEG_N, 0, ACC, 0);
    gemm_k<2><<<MN/64, 512, 0, stream>>>(xn, Ws0, xn, MN/64, xn, Ws0, xn, 0, xn, Ws0, xn,
                                         nullptr, nullptr, ACC, bs0);

    // cells: {Zc(SMa, held for edges), BDe(BIG1)} in ONE dispatch
    gemm_k<0><<<MC/64 + ME/64, 512, 0, stream>>>(
        xc, Wupa1, SMa, MC/64, xe, Wb1, BIG1, ME/64, xc, Wupa1, SMa,
        nullptr, nullptr, nullptr, nullptr);
    gather_k<0,1><<<MC/4, 256, 0, stream>>>(nullptr, nullptr, BIG1, csrUp, csrBd,
                                            offA, hist, 0, SEG_CB, ACC, 0);
    gemm_k<2><<<MC/64, 512, 0, stream>>>(xc, Ws2, xc, MC/64, xc, Ws2, xc, 0, xc, Ws2, xc,
                                         nullptr, nullptr, ACC, bs2);

    // edges: Ye(BIG1) from OLD xe; full-width gather + fused self
    gemm_k<0><<<ME/64, 512, 0, stream>>>(
        xe, Wupx1, BIG1, ME/64, xe, Wupx1, BIG1, 0, xe, Wupx1, BIG1,
        nullptr, nullptr, nullptr, nullptr);
    gather_k<1,1><<<ME/4, 256, 0, stream>>>(BIG1, SMa, SMb, csrUp, csrBd,
                                            offA, hist, SEG_E, SEG_EB, ACC, 0);
    gemm_k<2><<<ME/64, 512, 0, stream>>>(xe, Ws1, xe, ME/64, xe, Ws1, xe, 0, xe, Ws1, xe,
                                         nullptr, nullptr, ACC, bs1);
  }

  // ---- gated pooling: REFs into SMa/ACC/SMb, ONE segmented dual-A GEMM
  // (G aliases REF: per-block A2 rows fully staged before C rows written),
  // then one fused pool_all.
  conv3<<<14336, 256, 0, stream>>>(x_n, SMa, x_e, ACC, x_c, SMb, flag);
  {
    long np4 = (long)3 * NB * HD / 4;
    zero_f4<<<(int)((np4 + 255)/256), 256, 0, stream>>>(pooled, np4);
  }
  gemm_k<3><<<MN/64 + ME/64 + MC/64, 512, 0, stream>>>(
      xn, SMa, SMa, MN/64, xe, ACC, ACC, ME/64, xc, SMb, SMb,
      wtP, wtPref, nullptr, nullptr);
  pool_all<<<dim3(NB, 7), 256, 0, stream>>>(SMa, ACC, SMb, bpc, xn, xe, xc, pooled);

  // ---- readout
  conv_f2b<<<96, 256, 0, stream>>>(pooled, pooledb, (long)3 * NB * HD);
  readout1_mfma<<<dim3(2,2), 512, 0, stream>>>(pooledb, W1t, b1c, hbuf);
  readout2<<<NB, 64, 0, stream>>>(hbuf, W2c, b2c, d_out, flag);
}